// Round 3
// baseline (1167.531 us; speedup 1.0000x reference)
//
#include <hip/hip_runtime.h>
#include <math.h>

#define NB 8
#define NN 1024
#define NK 8
#define ND 256
#define ND2 512
#define NBK 64
#define EPSA 1e-8f
#define LNEPS 1e-5f
#define GSTEP (2.0f/31.0f)

using short8 = __attribute__((ext_vector_type(8))) short;
using short4v = __attribute__((ext_vector_type(4))) short;
using floatx4 = __attribute__((ext_vector_type(4))) float;

__device__ __forceinline__ short f2bf(float f) {
  unsigned u = __builtin_bit_cast(unsigned, f);
  u += 0x7fffu + ((u >> 16) & 1u);
  return (short)(u >> 16);
}

// ---------------- LN stats (mean, rstd) per input row ----------------
__global__ __launch_bounds__(256) void k_ln_stats(const float* __restrict__ inp,
                                                  float* __restrict__ stats) {
  const int row = blockIdx.x;
  const int t = threadIdx.x;
  const float v = inp[(size_t)row * ND + t];
  float s = v, ss = v * v;
#pragma unroll
  for (int m = 32; m >= 1; m >>= 1) { s += __shfl_xor(s, m); ss += __shfl_xor(ss, m); }
  __shared__ float red[8];
  const int wv = t >> 6;
  if ((t & 63) == 0) { red[wv] = s; red[4 + wv] = ss; }
  __syncthreads();
  if (t == 0) {
    const float S = red[0] + red[1] + red[2] + red[3];
    const float SS = red[4] + red[5] + red[6] + red[7];
    const float mean = S * (1.0f / ND);
    const float var = SS * (1.0f / ND) - mean * mean;
    stats[row * 2 + 0] = mean;
    stats[row * 2 + 1] = rsqrtf(var + LNEPS);
  }
}

// ---------------- all bf16 transposed weights in one launch ----------------
// [0,131072): w1T[n1][k] from ge_w1[k][n1]  (512x256)
// [131072,262144): w2T[n2][k2] from ge_w2[k2][n2] (256x512)
// [262144,327680): wkT[n][k] from wk[k][n] (256x256)
// [327680,393216): wvT
__global__ __launch_bounds__(256) void k_cvt_all(
    const float* __restrict__ w1, const float* __restrict__ w2,
    const float* __restrict__ wk, const float* __restrict__ wv,
    short* __restrict__ w1T, short* __restrict__ w2T,
    short* __restrict__ wkT, short* __restrict__ wvT) {
  const int idx = blockIdx.x * 256 + threadIdx.x;
  if (idx < 131072) {
    const int n = idx >> 8, k = idx & 255;
    w1T[idx] = f2bf(w1[(size_t)k * 512 + n]);
  } else if (idx < 262144) {
    const int i = idx - 131072;
    const int n = i >> 9, k = i & 511;
    w2T[i] = f2bf(w2[(size_t)k * 256 + n]);
  } else if (idx < 327680) {
    const int i = idx - 262144;
    const int n = i >> 8, k = i & 255;
    wkT[i] = f2bf(wk[(size_t)k * 256 + n]);
  } else {
    const int i = idx - 327680;
    const int n = i >> 8, k = i & 255;
    wvT[i] = f2bf(wv[(size_t)k * 256 + n]);
  }
}

// ---------------- GRU weight transpose (fp32): gT[arr][d][j] = w[arr][j][d] ----------------
__global__ __launch_bounds__(256) void k_gruT(const float* __restrict__ wih,
                                              const float* __restrict__ whh,
                                              float* __restrict__ gT) {
  const int j = blockIdx.x;           // 0..767
  const int arr = blockIdx.z;         // 0/1
  const int d = threadIdx.x;          // 0..255
  const float* src = arr ? whh : wih;
  gT[(size_t)arr * 196608 + (size_t)d * 768 + j] = src[(size_t)j * 256 + d];
}

// ---------------- k/v projection via bf16 MFMA ----------------
__global__ __launch_bounds__(256, 2) void k_gemm_kv_mfma(
    const float* __restrict__ inp, const float* __restrict__ stats,
    const float* __restrict__ nig, const float* __restrict__ nib,
    const short* __restrict__ wkT, const short* __restrict__ wvT,
    float* __restrict__ kout, float* __restrict__ vout) {
  __shared__ __align__(16) short tln[64 * 264];
  const short* __restrict__ WT = blockIdx.z ? wvT : wkT;
  float* __restrict__ out = blockIdx.z ? vout : kout;
  const int row0 = blockIdx.x * 64;
  const int t = threadIdx.x;
  const int wave = t >> 6, lane = t & 63, l15 = lane & 15, quad = lane >> 4;
  {
    const int r = t >> 2, sub = t & 3;
    const int row = row0 + r;
    const float m = stats[row * 2 + 0];
    const float rs = stats[row * 2 + 1];
    const float* xr = inp + (size_t)row * ND;
#pragma unroll
    for (int ii = 0; ii < 16; ii++) {
      const int d = sub * 4 + ii * 16;
      const float4 xv = *(const float4*)(xr + d);
      const float4 gg = *(const float4*)(nig + d);
      const float4 bb = *(const float4*)(nib + d);
      short4v pk;
      pk.x = f2bf((xv.x - m) * rs * gg.x + bb.x);
      pk.y = f2bf((xv.y - m) * rs * gg.y + bb.y);
      pk.z = f2bf((xv.z - m) * rs * gg.z + bb.z);
      pk.w = f2bf((xv.w - m) * rs * gg.w + bb.w);
      *(short4v*)&tln[r * 264 + d] = pk;
    }
  }
  __syncthreads();
  floatx4 acc[4][4];
#pragma unroll
  for (int mt = 0; mt < 4; mt++)
#pragma unroll
    for (int nt = 0; nt < 4; nt++) acc[mt][nt] = (floatx4){0.f, 0.f, 0.f, 0.f};
  const short* wp = WT + ((size_t)(wave * 64 + l15)) * 256 + quad * 8;
#pragma unroll
  for (int kk = 0; kk < 8; kk++) {
    short8 af[4];
#pragma unroll
    for (int mt = 0; mt < 4; mt++)
      af[mt] = *(const short8*)&tln[(mt * 16 + l15) * 264 + kk * 32 + quad * 8];
    short8 bf[4];
#pragma unroll
    for (int nt = 0; nt < 4; nt++)
      bf[nt] = *(const short8*)(wp + nt * 16 * 256 + kk * 32);
#pragma unroll
    for (int mt = 0; mt < 4; mt++)
#pragma unroll
      for (int nt = 0; nt < 4; nt++)
        acc[mt][nt] = __builtin_amdgcn_mfma_f32_16x16x32_bf16(af[mt], bf[nt], acc[mt][nt], 0, 0, 0);
  }
#pragma unroll
  for (int mt = 0; mt < 4; mt++)
#pragma unroll
    for (int nt = 0; nt < 4; nt++)
#pragma unroll
      for (int j = 0; j < 4; j++)
        out[(size_t)(row0 + mt * 16 + quad * 4 + j) * ND + wave * 64 + nt * 16 + l15] = acc[mt][nt][j];
}

// ---------------- per-(b,k): pos/scl + q = LN(slots)@wq ; zero upd ----------------
__global__ __launch_bounds__(256) void k_prep(
    const float* __restrict__ sf, const float* __restrict__ nsg,
    const float* __restrict__ nsb, const float* __restrict__ wq,
    float* __restrict__ q, float* __restrict__ pos, float* __restrict__ scl,
    float* __restrict__ upd) {
  const int bk = blockIdx.x;
  const int t = threadIdx.x;
  upd[bk * ND + t] = 0.f;
  const float v = sf[bk * 260 + t];
  float s = v, ss = v * v;
#pragma unroll
  for (int m = 32; m >= 1; m >>= 1) { s += __shfl_xor(s, m); ss += __shfl_xor(ss, m); }
  __shared__ float red[8];
  __shared__ float lnv[256];
  const int wv = t >> 6;
  if ((t & 63) == 0) { red[wv] = s; red[4 + wv] = ss; }
  __syncthreads();
  const float S = red[0] + red[1] + red[2] + red[3];
  const float SS = red[4] + red[5] + red[6] + red[7];
  const float mean = S * (1.0f / ND);
  const float var = SS * (1.0f / ND) - mean * mean;
  const float rstd = rsqrtf(var + LNEPS);
  lnv[t] = (v - mean) * rstd * nsg[t] + nsb[t];
  if (t < 2) {
    const float p = sf[bk * 260 + 256 + t];
    pos[bk * 2 + t] = fminf(fmaxf(p, -1.0f), 1.0f);
    const float sc = sf[bk * 260 + 258 + t];
    scl[bk * 2 + t] = fminf(fmaxf(sc, 1e-3f), 2.0f);
  }
  __syncthreads();
  float acc = 0.f;
#pragma unroll 8
  for (int e = 0; e < ND; e++) acc = fmaf(lnv[e], wq[e * ND + t], acc);
  q[bk * ND + t] = acc;
}

// ---------------- fused grid_enc pass (bf16 MFMA), 32 rows/block ----------------
__device__ __forceinline__ int h1idx(int row, int col) {
  return (row << 9) + ((((col >> 3) ^ (row & 7)) << 3) | (col & 7));
}

__global__ __launch_bounds__(256, 3) void k_fused_mfma(
    const float* __restrict__ kv,
    const float* __restrict__ pos, const float* __restrict__ scl,
    const float* __restrict__ gpw, const float* __restrict__ gpb,
    const float* __restrict__ lng, const float* __restrict__ lnb,
    const short* __restrict__ w1T, const float* __restrict__ b1,
    const short* __restrict__ w2T, const float* __restrict__ b2,
    const float* __restrict__ q, float* __restrict__ dots,
    const float* __restrict__ attn0, const float* __restrict__ denom,
    float* __restrict__ upd, const int mode) {
  __shared__ __align__(16) short smem[32 * 512];  // 32 KB; tln & h1 & dred alias
  short* tln = smem;
  short* h1 = smem;

  const int bk = blockIdx.y;
  const int n0 = blockIdx.x * 32;
  const int b = bk >> 3;
  const int t = threadIdx.x;
  const int wave = t >> 6;
  const int lane = t & 63;
  const int l15 = lane & 15;
  const int quad = lane >> 4;

  // ---- Phase A: tln = LN(kv + rel_enc) -> bf16 LDS (32 rows, 8 thr/row) ----
  {
    const float p0 = pos[bk * 2 + 0], p1 = pos[bk * 2 + 1];
    const float s0i = 1.0f / (scl[bk * 2 + 0] * 5.0f);
    const float s1i = 1.0f / (scl[bk * 2 + 1] * 5.0f);
    const int r = t >> 3;       // 0..31
    const int sub = t & 7;
    const int n = n0 + r;
    const float gx = -1.0f + GSTEP * (float)(n >> 5);
    const float gy = -1.0f + GSTEP * (float)(n & 31);
    const float rg0 = (gx - p0) * s0i;
    const float rg1 = (gy - p1) * s1i;
    const float* kvrow = kv + (size_t)(b * NN + n) * ND;
    float tv[32];
    float sum = 0.f, ssq = 0.f;
#pragma unroll
    for (int ii = 0; ii < 8; ii++) {
      const int d = sub * 4 + ii * 32;
      const float4 kv4 = *(const float4*)(kvrow + d);
      const float4 wa = *(const float4*)(gpw + d);
      const float4 wb = *(const float4*)(gpw + ND + d);
      const float4 pb = *(const float4*)(gpb + d);
      float v0 = kv4.x + rg0 * wa.x + rg1 * wb.x + pb.x;
      float v1 = kv4.y + rg0 * wa.y + rg1 * wb.y + pb.y;
      float v2 = kv4.z + rg0 * wa.z + rg1 * wb.z + pb.z;
      float v3 = kv4.w + rg0 * wa.w + rg1 * wb.w + pb.w;
      tv[ii * 4 + 0] = v0; sum += v0; ssq += v0 * v0;
      tv[ii * 4 + 1] = v1; sum += v1; ssq += v1 * v1;
      tv[ii * 4 + 2] = v2; sum += v2; ssq += v2 * v2;
      tv[ii * 4 + 3] = v3; sum += v3; ssq += v3 * v3;
    }
    sum += __shfl_xor(sum, 1); ssq += __shfl_xor(ssq, 1);
    sum += __shfl_xor(sum, 2); ssq += __shfl_xor(ssq, 2);
    sum += __shfl_xor(sum, 4); ssq += __shfl_xor(ssq, 4);
    const float mean = sum * (1.0f / ND);
    const float var = ssq * (1.0f / ND) - mean * mean;
    const float rstd = rsqrtf(var + LNEPS);
#pragma unroll
    for (int ii = 0; ii < 8; ii++) {
      const int d = sub * 4 + ii * 32;
      const float4 gg = *(const float4*)(lng + d);
      const float4 bb = *(const float4*)(lnb + d);
      short4v pk;
      pk.x = f2bf((tv[ii * 4 + 0] - mean) * rstd * gg.x + bb.x);
      pk.y = f2bf((tv[ii * 4 + 1] - mean) * rstd * gg.y + bb.y);
      pk.z = f2bf((tv[ii * 4 + 2] - mean) * rstd * gg.z + bb.z);
      pk.w = f2bf((tv[ii * 4 + 3] - mean) * rstd * gg.w + bb.w);
      *(short4v*)&tln[r * 264 + d] = pk;
    }
  }
  __syncthreads();

  // ---- GEMM1: h1 = relu(tln @ W1T^T + b1). Wave owns N1 cols [wave*128,+128) ----
  floatx4 acc1[2][8];
#pragma unroll
  for (int mt = 0; mt < 2; mt++)
#pragma unroll
    for (int nt = 0; nt < 8; nt++) acc1[mt][nt] = (floatx4){0.f, 0.f, 0.f, 0.f};

  const short* w1p = w1T + ((size_t)(wave * 128 + l15)) * 256 + quad * 8;
#pragma unroll
  for (int kk = 0; kk < 8; kk++) {
    short8 af[2];
#pragma unroll
    for (int mt = 0; mt < 2; mt++)
      af[mt] = *(const short8*)&tln[(mt * 16 + l15) * 264 + kk * 32 + quad * 8];
    short8 bf[8];
#pragma unroll
    for (int nt = 0; nt < 8; nt++)
      bf[nt] = *(const short8*)(w1p + nt * 16 * 256 + kk * 32);
#pragma unroll
    for (int mt = 0; mt < 2; mt++)
#pragma unroll
      for (int nt = 0; nt < 8; nt++)
        acc1[mt][nt] = __builtin_amdgcn_mfma_f32_16x16x32_bf16(af[mt], bf[nt], acc1[mt][nt], 0, 0, 0);
  }
  __syncthreads();  // all tln reads done before h1 overwrites

  {
    float b1v[8];
#pragma unroll
    for (int nt = 0; nt < 8; nt++) b1v[nt] = b1[wave * 128 + nt * 16 + l15];
#pragma unroll
    for (int mt = 0; mt < 2; mt++)
#pragma unroll
      for (int nt = 0; nt < 8; nt++) {
        const int col = wave * 128 + nt * 16 + l15;
#pragma unroll
        for (int j = 0; j < 4; j++) {
          const int row = mt * 16 + quad * 4 + j;
          h1[h1idx(row, col)] = f2bf(fmaxf(acc1[mt][nt][j] + b1v[nt], 0.f));
        }
      }
  }
  __syncthreads();

  // ---- GEMM2: o = h1 @ W2T^T (+b2). Wave owns N2 cols [wave*64,+64) ----
  floatx4 acc2[2][4];
#pragma unroll
  for (int mt = 0; mt < 2; mt++)
#pragma unroll
    for (int nt = 0; nt < 4; nt++) acc2[mt][nt] = (floatx4){0.f, 0.f, 0.f, 0.f};

  const short* w2p = w2T + ((size_t)(wave * 64 + l15)) * 512 + quad * 8;
#pragma unroll
  for (int kk = 0; kk < 16; kk++) {
    short8 af[2];
#pragma unroll
    for (int mt = 0; mt < 2; mt++) {
      const int row = mt * 16 + l15;
      af[mt] = *(const short8*)&h1[(row << 9) + (((kk * 4 + quad) ^ (row & 7)) << 3)];
    }
    short8 bf[4];
#pragma unroll
    for (int nt = 0; nt < 4; nt++)
      bf[nt] = *(const short8*)(w2p + nt * 16 * 512 + kk * 32);
#pragma unroll
    for (int mt = 0; mt < 2; mt++)
#pragma unroll
      for (int nt = 0; nt < 4; nt++)
        acc2[mt][nt] = __builtin_amdgcn_mfma_f32_16x16x32_bf16(af[mt], bf[nt], acc2[mt][nt], 0, 0, 0);
  }

  float b2v[4];
#pragma unroll
  for (int nt = 0; nt < 4; nt++) b2v[nt] = b2[wave * 64 + nt * 16 + l15];

  if (mode == 0) {
    float qn[4];
#pragma unroll
    for (int nt = 0; nt < 4; nt++) qn[nt] = q[bk * ND + wave * 64 + nt * 16 + l15];
    __syncthreads();  // done reading h1; reuse smem as float dred[4][32]
    float* dred = (float*)smem;
#pragma unroll
    for (int mt = 0; mt < 2; mt++)
#pragma unroll
      for (int j = 0; j < 4; j++) {
        float p = 0.f;
#pragma unroll
        for (int nt = 0; nt < 4; nt++)
          p = fmaf(acc2[mt][nt][j] + b2v[nt], qn[nt], p);
        p += __shfl_xor(p, 1); p += __shfl_xor(p, 2);
        p += __shfl_xor(p, 4); p += __shfl_xor(p, 8);
        if (l15 == 0) dred[wave * 32 + mt * 16 + quad * 4 + j] = p;
      }
    __syncthreads();
    if (t < 32) {
      const float s = dred[t] + dred[32 + t] + dred[64 + t] + dred[96 + t];
      dots[bk * NN + n0 + t] = s * 0.0625f;
    }
  } else {
    const float dn = 1.0f / denom[bk];
    float aw[2][4];
#pragma unroll
    for (int mt = 0; mt < 2; mt++)
#pragma unroll
      for (int j = 0; j < 4; j++)
        aw[mt][j] = (attn0[bk * NN + n0 + mt * 16 + quad * 4 + j] + EPSA) * dn;
#pragma unroll
    for (int nt = 0; nt < 4; nt++) {
      float s = 0.f;
#pragma unroll
      for (int mt = 0; mt < 2; mt++)
#pragma unroll
        for (int j = 0; j < 4; j++)
          s = fmaf(aw[mt][j], acc2[mt][nt][j] + b2v[nt], s);
      s += __shfl_xor(s, 16); s += __shfl_xor(s, 32);
      if (quad == 0) atomicAdd(upd + bk * ND + wave * 64 + nt * 16 + l15, s);
    }
  }
}

// ---------------- softmax over K per (b,n) ----------------
__global__ __launch_bounds__(256) void k_softmax(const float* __restrict__ dots,
                                                 float* __restrict__ attn0) {
  const int idx = blockIdx.x * 256 + threadIdx.x;
  const int b = idx >> 10, n = idx & 1023;
  float vals[NK];
  float mx = -1e30f;
#pragma unroll
  for (int k = 0; k < NK; k++) {
    vals[k] = dots[(size_t)(b * NK + k) * NN + n];
    mx = fmaxf(mx, vals[k]);
  }
  float s = 0.f;
#pragma unroll
  for (int k = 0; k < NK; k++) { vals[k] = expf(vals[k] - mx); s += vals[k]; }
  const float inv = 1.0f / s;
#pragma unroll
  for (int k = 0; k < NK; k++)
    attn0[(size_t)(b * NK + k) * NN + n] = vals[k] * inv;
}

// ---------------- fused: denom + pos_n + scl_n ----------------
__global__ __launch_bounds__(256) void k_reduce(const float* __restrict__ attn0,
                                                float* __restrict__ sf,
                                                float* __restrict__ denom) {
  const int bk = blockIdx.x, t = threadIdx.x;
  __shared__ float red[12];
  const int wv = t >> 6;
  float S = 0.f, G0 = 0.f, G1 = 0.f;
#pragma unroll
  for (int i = 0; i < 4; i++) {
    const int n = t + 256 * i;
    const float a = attn0[(size_t)bk * NN + n];
    const float gx = -1.0f + GSTEP * (float)(n >> 5);
    const float gy = -1.0f + GSTEP * (float)(n & 31);
    S += a; G0 = fmaf(a, gx, G0); G1 = fmaf(a, gy, G1);
  }
#pragma unroll
  for (int m = 32; m >= 1; m >>= 1) {
    S += __shfl_xor(S, m); G0 += __shfl_xor(G0, m); G1 += __shfl_xor(G1, m);
  }
  if ((t & 63) == 0) { red[wv] = S; red[4 + wv] = G0; red[8 + wv] = G1; }
  __syncthreads();
  const float St = red[0] + red[1] + red[2] + red[3];
  const float p0 = red[4] + red[5] + red[6] + red[7];
  const float p1 = red[8] + red[9] + red[10] + red[11];
  if (t == 0) denom[bk] = St + (float)NN * EPSA;
  __syncthreads();  // red about to be reused
  float S0 = 0.f, S1 = 0.f;
#pragma unroll
  for (int i = 0; i < 4; i++) {
    const int n = t + 256 * i;
    const float w = attn0[(size_t)bk * NN + n] + EPSA;
    const float d0 = (-1.0f + GSTEP * (float)(n >> 5)) - p0;
    const float d1 = (-1.0f + GSTEP * (float)(n & 31)) - p1;
    S0 = fmaf(w, d0 * d0, S0);
    S1 = fmaf(w, d1 * d1, S1);
  }
#pragma unroll
  for (int m = 32; m >= 1; m >>= 1) { S0 += __shfl_xor(S0, m); S1 += __shfl_xor(S1, m); }
  if ((t & 63) == 0) { red[wv] = S0; red[4 + wv] = S1; }
  __syncthreads();
  if (t == 0) {
    const float s0 = sqrtf(red[0] + red[1] + red[2] + red[3]);
    const float s1 = sqrtf(red[4] + red[5] + red[6] + red[7]);
    sf[bk * 260 + 256] = p0;
    sf[bk * 260 + 257] = p1;
    sf[bk * 260 + 258] = fminf(fmaxf(s0, 1e-3f), 2.0f);
    sf[bk * 260 + 259] = fminf(fmaxf(s1, 1e-3f), 2.0f);
  }
}

// ---------------- GRU slot update (transposed, coalesced weights) ----------------
__global__ __launch_bounds__(256) void k_gru(const float* __restrict__ upd,
                                             float* __restrict__ sf,
                                             const float* __restrict__ gT,
                                             const float* __restrict__ bih,
                                             const float* __restrict__ bhh) {
  const int bk = blockIdx.x, t = threadIdx.x;
  __shared__ float u[256], h[256];
  u[t] = upd[bk * ND + t];
  h[t] = sf[bk * 260 + t];
  __syncthreads();
  const float* wi = gT;             // [256][768]
  const float* wh = gT + 196608;    // [256][768]
  float a0 = 0.f, a1 = 0.f, a2 = 0.f, c0 = 0.f, c1 = 0.f, c2 = 0.f;
#pragma unroll 4
  for (int d = 0; d < ND; d++) {
    const float ud = u[d], hd = h[d];
    const float* wid = wi + (size_t)d * 768;
    const float* whd = wh + (size_t)d * 768;
    a0 = fmaf(ud, wid[t], a0);
    a1 = fmaf(ud, wid[256 + t], a1);
    a2 = fmaf(ud, wid[512 + t], a2);
    c0 = fmaf(hd, whd[t], c0);
    c1 = fmaf(hd, whd[256 + t], c1);
    c2 = fmaf(hd, whd[512 + t], c2);
  }
  const float r = 1.0f / (1.0f + expf(-(a0 + bih[t] + c0 + bhh[t])));
  const float z = 1.0f / (1.0f + expf(-(a1 + bih[256 + t] + c1 + bhh[256 + t])));
  const float nn = tanhf(a2 + bih[512 + t] + r * (c2 + bhh[512 + t]));
  sf[bk * 260 + t] = (1.0f - z) * nn + z * h[t];
}

// ---------------- finalize: conditioning + attn0 + rel_grid ----------------
__global__ __launch_bounds__(256) void k_finalize(
    const float* __restrict__ sf, const float* __restrict__ attn0,
    const float* __restrict__ pos, const float* __restrict__ scl,
    float* __restrict__ out) {
  const int bk = blockIdx.x, t = threadIdx.x;
  out[bk * 260 + t] = sf[bk * 260 + t];
  if (t < 4) out[bk * 260 + 256 + t] = sf[bk * 260 + 256 + t];
  const float p0 = pos[bk * 2 + 0], p1 = pos[bk * 2 + 1];
  const float s0 = scl[bk * 2 + 0] * 5.0f, s1 = scl[bk * 2 + 1] * 5.0f;
#pragma unroll
  for (int i = 0; i < 4; i++) {
    const int n = t + 256 * i;
    out[16640 + bk * NN + n] = attn0[(size_t)bk * NN + n];
    const float gx = -1.0f + GSTEP * (float)(n >> 5);
    const float gy = -1.0f + GSTEP * (float)(n & 31);
    float2 v;
    v.x = (gx - p0) / s0;
    v.y = (gy - p1) / s1;
    *(float2*)(out + 16640 + 65536 + ((size_t)bk * NN + n) * 2) = v;
  }
}

extern "C" void kernel_launch(void* const* d_in, const int* in_sizes, int n_in,
                              void* d_out, int out_size, void* d_ws, size_t ws_size,
                              hipStream_t stream) {
  const float* inputs   = (const float*)d_in[0];
  const float* cond     = (const float*)d_in[1];
  const float* ni_g     = (const float*)d_in[2];
  const float* ni_b     = (const float*)d_in[3];
  const float* ns_g     = (const float*)d_in[4];
  const float* ns_b     = (const float*)d_in[5];
  const float* wq       = (const float*)d_in[6];
  const float* wk       = (const float*)d_in[7];
  const float* wv       = (const float*)d_in[8];
  const float* gp_w     = (const float*)d_in[9];
  const float* gp_b     = (const float*)d_in[10];
  const float* ge_ln_g  = (const float*)d_in[11];
  const float* ge_ln_b  = (const float*)d_in[12];
  const float* ge_w1    = (const float*)d_in[13];
  const float* ge_b1    = (const float*)d_in[14];
  const float* ge_w2    = (const float*)d_in[15];
  const float* ge_b2    = (const float*)d_in[16];
  const float* gru_wih  = (const float*)d_in[17];
  const float* gru_whh  = (const float*)d_in[18];
  const float* gru_bih  = (const float*)d_in[19];
  const float* gru_bhh  = (const float*)d_in[20];

  float* ws   = (float*)d_ws;
  float* kbuf = ws;                  // 8*1024*256
  float* vbuf = kbuf + 2097152;      // 8*1024*256
  float* sf   = vbuf + 2097152;      // 64*260
  float* qb   = sf + 16640;          // 64*256
  float* posb = qb + 16384;          // 64*2 (padded)
  float* sclb = posb + 128;          // 64*2 (padded)
  float* dotsb = sclb + 128;         // 64*1024
  float* at0  = dotsb + 65536;       // 64*1024
  float* denb = at0 + 65536;         // 64
  float* updb = denb + 64;           // 64*256
  float* statb = updb + 16384;       // 8192*2
  float* gruT  = statb + 16384;      // 2*256*768
  short* w1T  = (short*)(gruT + 393216);  // 512*256 bf16
  short* w2T  = w1T + 131072;             // 256*512 bf16
  short* wkT  = w2T + 131072;             // 256*256 bf16
  short* wvT  = wkT + 65536;              // 256*256 bf16

  float* out = (float*)d_out;

  hipMemcpyAsync(sf, cond, 16640 * sizeof(float), hipMemcpyDeviceToDevice, stream);

  k_cvt_all<<<1536, 256, 0, stream>>>(ge_w1, ge_w2, wk, wv, w1T, w2T, wkT, wvT);
  k_gruT<<<dim3(768, 1, 2), 256, 0, stream>>>(gru_wih, gru_whh, gruT);
  k_ln_stats<<<NB * NN, 256, 0, stream>>>(inputs, statb);
  k_gemm_kv_mfma<<<dim3(128, 1, 2), 256, 0, stream>>>(inputs, statb, ni_g, ni_b,
                                                      wkT, wvT, kbuf, vbuf);

  for (int s = 0; s < 4; s++) {
    k_prep<<<NBK, 256, 0, stream>>>(sf, ns_g, ns_b, wq, qb, posb, sclb, updb);
    k_fused_mfma<<<dim3(32, NBK), 256, 0, stream>>>(
        kbuf, posb, sclb, gp_w, gp_b, ge_ln_g, ge_ln_b, w1T, ge_b1, w2T, ge_b2,
        qb, dotsb, nullptr, nullptr, nullptr, 0);
    k_softmax<<<32, 256, 0, stream>>>(dotsb, at0);
    k_reduce<<<NBK, 256, 0, stream>>>(at0, sf, denb);
    if (s < 3) {
      k_fused_mfma<<<dim3(32, NBK), 256, 0, stream>>>(
          vbuf, posb, sclb, gp_w, gp_b, ge_ln_g, ge_ln_b, w1T, ge_b1, w2T, ge_b2,
          nullptr, nullptr, at0, denb, updb, 1);
      k_gru<<<NBK, 256, 0, stream>>>(updb, sf, gruT, gru_bih, gru_bhh);
    }
  }

  k_finalize<<<NBK, 256, 0, stream>>>(sf, at0, posb, sclb, out);
}

// Round 5
// 869.307 us; speedup vs baseline: 1.3431x; 1.3431x over previous
//
#include <hip/hip_runtime.h>
#include <math.h>

#define NB 8
#define NN 1024
#define NK 8
#define ND 256
#define ND2 512
#define NBK 64
#define EPSA 1e-8f
#define LNEPS 1e-5f
#define GSTEP (2.0f/31.0f)

using short8 = __attribute__((ext_vector_type(8))) short;
using short4v = __attribute__((ext_vector_type(4))) short;
using floatx4 = __attribute__((ext_vector_type(4))) float;

__device__ __forceinline__ short f2bf(float f) {
  unsigned u = __builtin_bit_cast(unsigned, f);
  u += 0x7fffu + ((u >> 16) & 1u);
  return (short)(u >> 16);
}

// ---------------- all weight conversions in one launch ----------------
// [0,131072): w1T[n1][k] ; [131072,262144): w2T[n2][k2] ; [262144,327680): wkT ;
// [327680,393216): wvT ; [393216,786432): gruT fp32 [arr][d][j]
__global__ __launch_bounds__(256) void k_cvt_all(
    const float* __restrict__ w1, const float* __restrict__ w2,
    const float* __restrict__ wk, const float* __restrict__ wv,
    const float* __restrict__ wih, const float* __restrict__ whh,
    short* __restrict__ w1T, short* __restrict__ w2T,
    short* __restrict__ wkT, short* __restrict__ wvT,
    float* __restrict__ gT) {
  const int idx = blockIdx.x * 256 + threadIdx.x;
  if (idx < 131072) {
    const int n = idx >> 8, k = idx & 255;
    w1T[idx] = f2bf(w1[(size_t)k * 512 + n]);
  } else if (idx < 262144) {
    const int i = idx - 131072;
    const int n = i >> 9, k = i & 511;
    w2T[i] = f2bf(w2[(size_t)k * 256 + n]);
  } else if (idx < 327680) {
    const int i = idx - 262144;
    const int n = i >> 8, k = i & 255;
    wkT[i] = f2bf(wk[(size_t)k * 256 + n]);
  } else if (idx < 393216) {
    const int i = idx - 327680;
    const int n = i >> 8, k = i & 255;
    wvT[i] = f2bf(wv[(size_t)k * 256 + n]);
  } else {
    const int i2 = idx - 393216;          // 0..393215
    const float* src = (i2 >= 196608) ? whh : wih;
    // BUGFIX r4: 196608 is NOT a power of two; `i2 & 196607` scrambled whh.
    const int i3 = (i2 >= 196608) ? (i2 - 196608) : i2;
    const int d = i3 / 768, j = i3 % 768;
    gT[i2] = src[(size_t)j * 256 + d];
  }
}

// ---------------- k/v projection via bf16 MFMA (LN stats inline) ----------------
__global__ __launch_bounds__(256, 2) void k_gemm_kv_mfma(
    const float* __restrict__ inp,
    const float* __restrict__ nig, const float* __restrict__ nib,
    const short* __restrict__ wkT, const short* __restrict__ wvT,
    float* __restrict__ kout, float* __restrict__ vout) {
  __shared__ __align__(16) short tln[64 * 264];
  const short* __restrict__ WT = blockIdx.z ? wvT : wkT;
  float* __restrict__ out = blockIdx.z ? vout : kout;
  const int row0 = blockIdx.x * 64;
  const int t = threadIdx.x;
  const int wave = t >> 6, lane = t & 63, l15 = lane & 15, quad = lane >> 4;
  {
    const int r = t >> 2, sub = t & 3;
    const float* xr = inp + (size_t)(row0 + r) * ND;
    float tv[64];
    float sum = 0.f, ssq = 0.f;
#pragma unroll
    for (int ii = 0; ii < 16; ii++) {
      const int d = sub * 4 + ii * 16;
      const float4 xv = *(const float4*)(xr + d);
      tv[ii * 4 + 0] = xv.x; sum += xv.x; ssq += xv.x * xv.x;
      tv[ii * 4 + 1] = xv.y; sum += xv.y; ssq += xv.y * xv.y;
      tv[ii * 4 + 2] = xv.z; sum += xv.z; ssq += xv.z * xv.z;
      tv[ii * 4 + 3] = xv.w; sum += xv.w; ssq += xv.w * xv.w;
    }
    sum += __shfl_xor(sum, 1); ssq += __shfl_xor(ssq, 1);
    sum += __shfl_xor(sum, 2); ssq += __shfl_xor(ssq, 2);
    const float mean = sum * (1.0f / ND);
    const float var = ssq * (1.0f / ND) - mean * mean;
    const float rstd = rsqrtf(var + LNEPS);
#pragma unroll
    for (int ii = 0; ii < 16; ii++) {
      const int d = sub * 4 + ii * 16;
      const float4 gg = *(const float4*)(nig + d);
      const float4 bb = *(const float4*)(nib + d);
      short4v pk;
      pk.x = f2bf((tv[ii * 4 + 0] - mean) * rstd * gg.x + bb.x);
      pk.y = f2bf((tv[ii * 4 + 1] - mean) * rstd * gg.y + bb.y);
      pk.z = f2bf((tv[ii * 4 + 2] - mean) * rstd * gg.z + bb.z);
      pk.w = f2bf((tv[ii * 4 + 3] - mean) * rstd * gg.w + bb.w);
      *(short4v*)&tln[r * 264 + d] = pk;
    }
  }
  __syncthreads();
  floatx4 acc[4][4];
#pragma unroll
  for (int mt = 0; mt < 4; mt++)
#pragma unroll
    for (int nt = 0; nt < 4; nt++) acc[mt][nt] = (floatx4){0.f, 0.f, 0.f, 0.f};
  const short* wp = WT + ((size_t)(wave * 64 + l15)) * 256 + quad * 8;
#pragma unroll
  for (int kk = 0; kk < 8; kk++) {
    short8 af[4];
#pragma unroll
    for (int mt = 0; mt < 4; mt++)
      af[mt] = *(const short8*)&tln[(mt * 16 + l15) * 264 + kk * 32 + quad * 8];
    short8 bf[4];
#pragma unroll
    for (int nt = 0; nt < 4; nt++)
      bf[nt] = *(const short8*)(wp + nt * 16 * 256 + kk * 32);
#pragma unroll
    for (int mt = 0; mt < 4; mt++)
#pragma unroll
      for (int nt = 0; nt < 4; nt++)
        acc[mt][nt] = __builtin_amdgcn_mfma_f32_16x16x32_bf16(af[mt], bf[nt], acc[mt][nt], 0, 0, 0);
  }
#pragma unroll
  for (int mt = 0; mt < 4; mt++)
#pragma unroll
    for (int nt = 0; nt < 4; nt++)
#pragma unroll
      for (int j = 0; j < 4; j++)
        out[(size_t)(row0 + mt * 16 + quad * 4 + j) * ND + wave * 64 + nt * 16 + l15] = acc[mt][nt][j];
}

// ---------------- first prep: pos/scl + q = LN(slots)@wq ; zero upd/stage ----------------
__global__ __launch_bounds__(256) void k_prep(
    const float* __restrict__ sf, const float* __restrict__ nsg,
    const float* __restrict__ nsb, const float* __restrict__ wq,
    float* __restrict__ q, float* __restrict__ pos, float* __restrict__ scl,
    float* __restrict__ upd, float* __restrict__ stage) {
  const int bk = blockIdx.x;
  const int t = threadIdx.x;
  upd[bk * ND + t] = 0.f;
  if (t < 8) stage[bk * 8 + t] = 0.f;
  const float v = sf[bk * 260 + t];
  float s = v, ss = v * v;
#pragma unroll
  for (int m = 32; m >= 1; m >>= 1) { s += __shfl_xor(s, m); ss += __shfl_xor(ss, m); }
  __shared__ float red[8];
  __shared__ float lnv[256];
  const int wv = t >> 6;
  if ((t & 63) == 0) { red[wv] = s; red[4 + wv] = ss; }
  __syncthreads();
  const float S = red[0] + red[1] + red[2] + red[3];
  const float SS = red[4] + red[5] + red[6] + red[7];
  const float mean = S * (1.0f / ND);
  const float var = SS * (1.0f / ND) - mean * mean;
  const float rstd = rsqrtf(var + LNEPS);
  lnv[t] = (v - mean) * rstd * nsg[t] + nsb[t];
  if (t < 2) {
    const float p = sf[bk * 260 + 256 + t];
    pos[bk * 2 + t] = fminf(fmaxf(p, -1.0f), 1.0f);
    const float sc = sf[bk * 260 + 258 + t];
    scl[bk * 2 + t] = fminf(fmaxf(sc, 1e-3f), 2.0f);
  }
  __syncthreads();
  float acc = 0.f;
#pragma unroll 8
  for (int e = 0; e < ND; e++) acc = fmaf(lnv[e], wq[e * ND + t], acc);
  q[bk * ND + t] = acc;
}

// ---------------- fused grid_enc pass: 64 rows/block, h1 chunked (50 KB LDS) ----------------
__global__ __launch_bounds__(256, 3) void k_fused_mfma(
    const float* __restrict__ kv,
    const float* __restrict__ pos, const float* __restrict__ scl,
    const float* __restrict__ gpw, const float* __restrict__ gpb,
    const float* __restrict__ lng, const float* __restrict__ lnb,
    const short* __restrict__ w1T, const float* __restrict__ b1,
    const short* __restrict__ w2T, const float* __restrict__ b2,
    const float* __restrict__ q, float* __restrict__ dots,
    const float* __restrict__ attn0, const float* __restrict__ stage,
    float* __restrict__ upd, const int mode) {
  __shared__ __align__(16) short smem[64 * 264 + 64 * 136];  // tln 33KB + h1c 17KB
  short* tln = smem;
  short* h1c = smem + 64 * 264;

  const int bk = blockIdx.y;
  const int n0 = blockIdx.x * 64;
  const int b = bk >> 3;
  const int t = threadIdx.x;
  const int wave = t >> 6;
  const int lane = t & 63;
  const int l15 = lane & 15;
  const int quad = lane >> 4;

  // ---- Phase A: tln = LN(kv + rel_enc) -> bf16 LDS (64 rows, 4 thr/row) ----
  {
    const float p0 = pos[bk * 2 + 0], p1 = pos[bk * 2 + 1];
    const float s0i = 1.0f / (scl[bk * 2 + 0] * 5.0f);
    const float s1i = 1.0f / (scl[bk * 2 + 1] * 5.0f);
    const int r = t >> 2;
    const int sub = t & 3;
    const int n = n0 + r;
    const float gx = -1.0f + GSTEP * (float)(n >> 5);
    const float gy = -1.0f + GSTEP * (float)(n & 31);
    const float rg0 = (gx - p0) * s0i;
    const float rg1 = (gy - p1) * s1i;
    const float* kvrow = kv + (size_t)(b * NN + n) * ND;
    float tv[64];
    float sum = 0.f, ssq = 0.f;
#pragma unroll
    for (int ii = 0; ii < 16; ii++) {
      const int d = sub * 4 + ii * 16;
      const float4 kv4 = *(const float4*)(kvrow + d);
      const float4 wa = *(const float4*)(gpw + d);
      const float4 wb = *(const float4*)(gpw + ND + d);
      const float4 pb = *(const float4*)(gpb + d);
      float v0 = kv4.x + rg0 * wa.x + rg1 * wb.x + pb.x;
      float v1 = kv4.y + rg0 * wa.y + rg1 * wb.y + pb.y;
      float v2 = kv4.z + rg0 * wa.z + rg1 * wb.z + pb.z;
      float v3 = kv4.w + rg0 * wa.w + rg1 * wb.w + pb.w;
      tv[ii * 4 + 0] = v0; sum += v0; ssq += v0 * v0;
      tv[ii * 4 + 1] = v1; sum += v1; ssq += v1 * v1;
      tv[ii * 4 + 2] = v2; sum += v2; ssq += v2 * v2;
      tv[ii * 4 + 3] = v3; sum += v3; ssq += v3 * v3;
    }
    sum += __shfl_xor(sum, 1); ssq += __shfl_xor(ssq, 1);
    sum += __shfl_xor(sum, 2); ssq += __shfl_xor(ssq, 2);
    const float mean = sum * (1.0f / ND);
    const float var = ssq * (1.0f / ND) - mean * mean;
    const float rstd = rsqrtf(var + LNEPS);
#pragma unroll
    for (int ii = 0; ii < 16; ii++) {
      const int d = sub * 4 + ii * 16;
      const float4 gg = *(const float4*)(lng + d);
      const float4 bb = *(const float4*)(lnb + d);
      short4v pk;
      pk.x = f2bf((tv[ii * 4 + 0] - mean) * rstd * gg.x + bb.x);
      pk.y = f2bf((tv[ii * 4 + 1] - mean) * rstd * gg.y + bb.y);
      pk.z = f2bf((tv[ii * 4 + 2] - mean) * rstd * gg.z + bb.z);
      pk.w = f2bf((tv[ii * 4 + 3] - mean) * rstd * gg.w + bb.w);
      *(short4v*)&tln[r * 264 + d] = pk;
    }
  }
  __syncthreads();

  // ---- Chunked GEMM1/GEMM2: 4 chunks of 128 h1-cols ----
  floatx4 acc2[4][4];
#pragma unroll
  for (int mt = 0; mt < 4; mt++)
#pragma unroll
    for (int nt = 0; nt < 4; nt++) acc2[mt][nt] = (floatx4){0.f, 0.f, 0.f, 0.f};

#pragma unroll
  for (int c = 0; c < 4; c++) {
    // GEMM1 chunk: wave covers 32 cols [c*128 + wave*32, +32), all 64 rows
    floatx4 acc1[4][2];
#pragma unroll
    for (int mt = 0; mt < 4; mt++)
#pragma unroll
      for (int nt = 0; nt < 2; nt++) acc1[mt][nt] = (floatx4){0.f, 0.f, 0.f, 0.f};
    const short* w1p = w1T + ((size_t)(c * 128 + wave * 32 + l15)) * 256 + quad * 8;
#pragma unroll
    for (int kk = 0; kk < 8; kk++) {
      short8 af[4];
#pragma unroll
      for (int mt = 0; mt < 4; mt++)
        af[mt] = *(const short8*)&tln[(mt * 16 + l15) * 264 + kk * 32 + quad * 8];
      short8 bf[2];
#pragma unroll
      for (int nt = 0; nt < 2; nt++)
        bf[nt] = *(const short8*)(w1p + nt * 16 * 256 + kk * 32);
#pragma unroll
      for (int mt = 0; mt < 4; mt++)
#pragma unroll
        for (int nt = 0; nt < 2; nt++)
          acc1[mt][nt] = __builtin_amdgcn_mfma_f32_16x16x32_bf16(af[mt], bf[nt], acc1[mt][nt], 0, 0, 0);
    }
    if (c > 0) __syncthreads();  // prior GEMM2 done reading h1c
    {
      float b1v[2];
#pragma unroll
      for (int nt = 0; nt < 2; nt++) b1v[nt] = b1[c * 128 + wave * 32 + nt * 16 + l15];
#pragma unroll
      for (int mt = 0; mt < 4; mt++)
#pragma unroll
        for (int nt = 0; nt < 2; nt++) {
          const int cl = wave * 32 + nt * 16 + l15;
#pragma unroll
          for (int j = 0; j < 4; j++)
            h1c[(mt * 16 + quad * 4 + j) * 136 + cl] = f2bf(fmaxf(acc1[mt][nt][j] + b1v[nt], 0.f));
        }
    }
    __syncthreads();
    // GEMM2 partial: wave covers 64 out cols, k2 in [c*128, +128)
    const short* w2p = w2T + ((size_t)(wave * 64 + l15)) * 512 + c * 128 + quad * 8;
#pragma unroll
    for (int kk = 0; kk < 4; kk++) {
      short8 af[4];
#pragma unroll
      for (int mt = 0; mt < 4; mt++)
        af[mt] = *(const short8*)&h1c[(mt * 16 + l15) * 136 + kk * 32 + quad * 8];
      short8 bf[4];
#pragma unroll
      for (int nt = 0; nt < 4; nt++)
        bf[nt] = *(const short8*)(w2p + nt * 16 * 512 + kk * 32);
#pragma unroll
      for (int mt = 0; mt < 4; mt++)
#pragma unroll
        for (int nt = 0; nt < 4; nt++)
          acc2[mt][nt] = __builtin_amdgcn_mfma_f32_16x16x32_bf16(af[mt], bf[nt], acc2[mt][nt], 0, 0, 0);
    }
  }

  float b2v[4];
#pragma unroll
  for (int nt = 0; nt < 4; nt++) b2v[nt] = b2[wave * 64 + nt * 16 + l15];

  if (mode == 0) {
    float qn[4];
#pragma unroll
    for (int nt = 0; nt < 4; nt++) qn[nt] = q[bk * ND + wave * 64 + nt * 16 + l15];
    __syncthreads();  // done with h1c/tln; reuse smem as float dred[4][64]
    float* dred = (float*)smem;
#pragma unroll
    for (int mt = 0; mt < 4; mt++)
#pragma unroll
      for (int j = 0; j < 4; j++) {
        float p = 0.f;
#pragma unroll
        for (int nt = 0; nt < 4; nt++)
          p = fmaf(acc2[mt][nt][j] + b2v[nt], qn[nt], p);
        p += __shfl_xor(p, 1); p += __shfl_xor(p, 2);
        p += __shfl_xor(p, 4); p += __shfl_xor(p, 8);
        if (l15 == 0) dred[wave * 64 + mt * 16 + quad * 4 + j] = p;
      }
    __syncthreads();
    if (t < 64) {
      const float s = dred[t] + dred[64 + t] + dred[128 + t] + dred[192 + t];
      dots[bk * NN + n0 + t] = s * 0.0625f;
    }
  } else {
    const float dn = 1.0f / (stage[bk * 8 + 0] + (float)NN * EPSA);
    float aw[4][4];
#pragma unroll
    for (int mt = 0; mt < 4; mt++)
#pragma unroll
      for (int j = 0; j < 4; j++)
        aw[mt][j] = (attn0[bk * NN + n0 + mt * 16 + quad * 4 + j] + EPSA) * dn;
#pragma unroll
    for (int nt = 0; nt < 4; nt++) {
      float s = 0.f;
#pragma unroll
      for (int mt = 0; mt < 4; mt++)
#pragma unroll
        for (int j = 0; j < 4; j++)
          s = fmaf(aw[mt][j], acc2[mt][nt][j] + b2v[nt], s);
      s += __shfl_xor(s, 16); s += __shfl_xor(s, 32);
      if (quad == 0) atomicAdd(upd + bk * ND + wave * 64 + nt * 16 + l15, s);
    }
  }
}

// ---------------- softmax over K + one-pass moment sums -> stage ----------------
// stage[bk*8 + {0:S, 1:G0, 2:G1, 3:Q0, 4:Q1}]
__global__ __launch_bounds__(256) void k_softmax_reduce(
    const float* __restrict__ dots, float* __restrict__ attn0,
    float* __restrict__ stage) {
  const int t = threadIdx.x;
  const int idx = blockIdx.x * 256 + t;
  const int b = idx >> 10, n = idx & 1023;
  const int lane = t & 63, wave = t >> 6;
  float vals[NK];
  float mx = -1e30f;
#pragma unroll
  for (int k = 0; k < NK; k++) {
    vals[k] = dots[(size_t)(b * NK + k) * NN + n];
    mx = fmaxf(mx, vals[k]);
  }
  float s = 0.f;
#pragma unroll
  for (int k = 0; k < NK; k++) { vals[k] = expf(vals[k] - mx); s += vals[k]; }
  const float inv = 1.0f / s;
  const float gx = -1.0f + GSTEP * (float)(n >> 5);
  const float gy = -1.0f + GSTEP * (float)(n & 31);
  const float gx2 = gx * gx, gy2 = gy * gy;
  float sk[NK][5];
#pragma unroll
  for (int k = 0; k < NK; k++) {
    const float a = vals[k] * inv;
    attn0[(size_t)(b * NK + k) * NN + n] = a;
    const float w = a + EPSA;
    sk[k][0] = a;
    sk[k][1] = a * gx;
    sk[k][2] = a * gy;
    sk[k][3] = w * gx2;
    sk[k][4] = w * gy2;
  }
#pragma unroll
  for (int m = 32; m >= 1; m >>= 1)
#pragma unroll
    for (int k = 0; k < NK; k++)
#pragma unroll
      for (int c = 0; c < 5; c++)
        sk[k][c] += __shfl_xor(sk[k][c], m);
  __shared__ float red[4][40];
  if (lane == 0) {
#pragma unroll
    for (int k = 0; k < NK; k++)
#pragma unroll
      for (int c = 0; c < 5; c++)
        red[wave][k * 5 + c] = sk[k][c];
  }
  __syncthreads();
  if (t < 40) {
    const float tot = red[0][t] + red[1][t] + red[2][t] + red[3][t];
    const int k = t / 5, c = t % 5;
    atomicAdd(&stage[(b * NK + k) * 8 + c], tot);
  }
}

// ---------------- GRU + next-iter prep (merged) ----------------
__global__ __launch_bounds__(256) void k_gruprep(
    float* __restrict__ upd, float* __restrict__ sf,
    const float* __restrict__ gT,
    const float* __restrict__ bih, const float* __restrict__ bhh,
    const float* __restrict__ nsg, const float* __restrict__ nsb,
    const float* __restrict__ wq,
    float* __restrict__ q, float* __restrict__ pos, float* __restrict__ scl,
    float* __restrict__ stage) {
  const int bk = blockIdx.x, t = threadIdx.x;
  __shared__ float u[256], h[256], lnv[256], red[8];
  u[t] = upd[bk * ND + t];
  h[t] = sf[bk * 260 + t];
  __syncthreads();
  const float* wi = gT;             // [256][768]
  const float* wh = gT + 196608;    // [256][768]
  float a0 = 0.f, a1 = 0.f, a2 = 0.f, c0 = 0.f, c1 = 0.f, c2 = 0.f;
#pragma unroll 4
  for (int d = 0; d < ND; d++) {
    const float ud = u[d], hd = h[d];
    const float* wid = wi + (size_t)d * 768;
    const float* whd = wh + (size_t)d * 768;
    a0 = fmaf(ud, wid[t], a0);
    a1 = fmaf(ud, wid[256 + t], a1);
    a2 = fmaf(ud, wid[512 + t], a2);
    c0 = fmaf(hd, whd[t], c0);
    c1 = fmaf(hd, whd[256 + t], c1);
    c2 = fmaf(hd, whd[512 + t], c2);
  }
  const float r = 1.0f / (1.0f + expf(-(a0 + bih[t] + c0 + bhh[t])));
  const float z = 1.0f / (1.0f + expf(-(a1 + bih[256 + t] + c1 + bhh[256 + t])));
  const float nw = tanhf(a2 + bih[512 + t] + r * (c2 + bhh[512 + t]));
  const float ns = (1.0f - z) * nw + z * h[t];
  sf[bk * 260 + t] = ns;
  // LN of new slots + q projection
  float s2 = ns, ss = ns * ns;
#pragma unroll
  for (int m = 32; m >= 1; m >>= 1) { s2 += __shfl_xor(s2, m); ss += __shfl_xor(ss, m); }
  const int wv = t >> 6;
  if ((t & 63) == 0) { red[wv] = s2; red[4 + wv] = ss; }
  __syncthreads();
  const float S = red[0] + red[1] + red[2] + red[3];
  const float SS = red[4] + red[5] + red[6] + red[7];
  const float mean = S * (1.0f / ND);
  const float var = SS * (1.0f / ND) - mean * mean;
  const float rstd = rsqrtf(var + LNEPS);
  lnv[t] = (ns - mean) * rstd * nsg[t] + nsb[t];
  __syncthreads();
  float acc = 0.f;
#pragma unroll 8
  for (int e = 0; e < ND; e++) acc = fmaf(lnv[e], wq[e * ND + t], acc);
  q[bk * ND + t] = acc;
  // pos_n / scl_n from stage moments (one-pass: Sum g over grid = 0)
  if (t == 0) {
    const float Sa = stage[bk * 8 + 0];
    const float G0 = stage[bk * 8 + 1];
    const float G1 = stage[bk * 8 + 2];
    const float Q0 = stage[bk * 8 + 3];
    const float Q1 = stage[bk * 8 + 4];
    const float W = Sa + (float)NN * EPSA;
    const float sc0 = sqrtf(fmaxf(Q0 - 2.0f * G0 * G0 + G0 * G0 * W, 0.f));
    const float sc1 = sqrtf(fmaxf(Q1 - 2.0f * G1 * G1 + G1 * G1 * W, 0.f));
    const float sc0c = fminf(fmaxf(sc0, 1e-3f), 2.0f);
    const float sc1c = fminf(fmaxf(sc1, 1e-3f), 2.0f);
    sf[bk * 260 + 256] = G0;
    sf[bk * 260 + 257] = G1;
    sf[bk * 260 + 258] = sc0c;
    sf[bk * 260 + 259] = sc1c;
    pos[bk * 2 + 0] = fminf(fmaxf(G0, -1.0f), 1.0f);
    pos[bk * 2 + 1] = fminf(fmaxf(G1, -1.0f), 1.0f);
    scl[bk * 2 + 0] = sc0c;
    scl[bk * 2 + 1] = sc1c;
  }
  __syncthreads();  // t==0's stage reads done before zeroing
  if (t < 8) stage[bk * 8 + t] = 0.f;
  upd[bk * ND + t] = 0.f;
}

// ---------------- finalize: conditioning(+tail from stage) + attn0 + rel_grid ----------------
__global__ __launch_bounds__(256) void k_finalize(
    const float* __restrict__ sf, const float* __restrict__ attn0,
    const float* __restrict__ pos, const float* __restrict__ scl,
    const float* __restrict__ stage, float* __restrict__ out) {
  const int bk = blockIdx.x, t = threadIdx.x;
  out[bk * 260 + t] = sf[bk * 260 + t];
  if (t == 0) {
    const float Sa = stage[bk * 8 + 0];
    const float G0 = stage[bk * 8 + 1];
    const float G1 = stage[bk * 8 + 2];
    const float Q0 = stage[bk * 8 + 3];
    const float Q1 = stage[bk * 8 + 4];
    const float W = Sa + (float)NN * EPSA;
    const float sc0 = sqrtf(fmaxf(Q0 - 2.0f * G0 * G0 + G0 * G0 * W, 0.f));
    const float sc1 = sqrtf(fmaxf(Q1 - 2.0f * G1 * G1 + G1 * G1 * W, 0.f));
    out[bk * 260 + 256] = G0;
    out[bk * 260 + 257] = G1;
    out[bk * 260 + 258] = fminf(fmaxf(sc0, 1e-3f), 2.0f);
    out[bk * 260 + 259] = fminf(fmaxf(sc1, 1e-3f), 2.0f);
  }
  const float p0 = pos[bk * 2 + 0], p1 = pos[bk * 2 + 1];
  const float s0 = scl[bk * 2 + 0] * 5.0f, s1 = scl[bk * 2 + 1] * 5.0f;
#pragma unroll
  for (int i = 0; i < 4; i++) {
    const int n = t + 256 * i;
    out[16640 + bk * NN + n] = attn0[(size_t)bk * NN + n];
    const float gx = -1.0f + GSTEP * (float)(n >> 5);
    const float gy = -1.0f + GSTEP * (float)(n & 31);
    float2 v;
    v.x = (gx - p0) / s0;
    v.y = (gy - p1) / s1;
    *(float2*)(out + 16640 + 65536 + ((size_t)bk * NN + n) * 2) = v;
  }
}

extern "C" void kernel_launch(void* const* d_in, const int* in_sizes, int n_in,
                              void* d_out, int out_size, void* d_ws, size_t ws_size,
                              hipStream_t stream) {
  const float* inputs   = (const float*)d_in[0];
  const float* cond     = (const float*)d_in[1];
  const float* ni_g     = (const float*)d_in[2];
  const float* ni_b     = (const float*)d_in[3];
  const float* ns_g     = (const float*)d_in[4];
  const float* ns_b     = (const float*)d_in[5];
  const float* wq       = (const float*)d_in[6];
  const float* wk       = (const float*)d_in[7];
  const float* wv       = (const float*)d_in[8];
  const float* gp_w     = (const float*)d_in[9];
  const float* gp_b     = (const float*)d_in[10];
  const float* ge_ln_g  = (const float*)d_in[11];
  const float* ge_ln_b  = (const float*)d_in[12];
  const float* ge_w1    = (const float*)d_in[13];
  const float* ge_b1    = (const float*)d_in[14];
  const float* ge_w2    = (const float*)d_in[15];
  const float* ge_b2    = (const float*)d_in[16];
  const float* gru_wih  = (const float*)d_in[17];
  const float* gru_whh  = (const float*)d_in[18];
  const float* gru_bih  = (const float*)d_in[19];
  const float* gru_bhh  = (const float*)d_in[20];

  float* ws   = (float*)d_ws;
  float* kbuf = ws;                  // 8*1024*256
  float* vbuf = kbuf + 2097152;      // 8*1024*256
  float* sf   = vbuf + 2097152;      // 64*260
  float* qb   = sf + 16640;          // 64*256
  float* posb = qb + 16384;          // 64*2 (padded)
  float* sclb = posb + 128;          // 64*2 (padded)
  float* dotsb = sclb + 128;         // 64*1024
  float* at0  = dotsb + 65536;       // 64*1024
  float* updb = at0 + 65536;         // 64*256
  float* stag = updb + 16384;        // 64*8
  float* gruT = stag + 512;          // 2*256*768
  short* w1T  = (short*)(gruT + 393216);  // 512*256 bf16
  short* w2T  = w1T + 131072;             // 256*512 bf16
  short* wkT  = w2T + 131072;             // 256*256 bf16
  short* wvT  = wkT + 65536;              // 256*256 bf16

  float* out = (float*)d_out;

  hipMemcpyAsync(sf, cond, 16640 * sizeof(float), hipMemcpyDeviceToDevice, stream);

  k_cvt_all<<<3072, 256, 0, stream>>>(ge_w1, ge_w2, wk, wv, gru_wih, gru_whh,
                                      w1T, w2T, wkT, wvT, gruT);
  k_gemm_kv_mfma<<<dim3(128, 1, 2), 256, 0, stream>>>(inputs, ni_g, ni_b,
                                                      wkT, wvT, kbuf, vbuf);
  k_prep<<<NBK, 256, 0, stream>>>(sf, ns_g, ns_b, wq, qb, posb, sclb, updb, stag);

  for (int s = 0; s < 4; s++) {
    k_fused_mfma<<<dim3(16, NBK), 256, 0, stream>>>(
        kbuf, posb, sclb, gp_w, gp_b, ge_ln_g, ge_ln_b, w1T, ge_b1, w2T, ge_b2,
        qb, dotsb, at0, stag, updb, 0);
    k_softmax_reduce<<<32, 256, 0, stream>>>(dotsb, at0, stag);
    if (s < 3) {
      k_fused_mfma<<<dim3(16, NBK), 256, 0, stream>>>(
          vbuf, posb, sclb, gp_w, gp_b, ge_ln_g, ge_ln_b, w1T, ge_b1, w2T, ge_b2,
          qb, dotsb, at0, stag, updb, 1);
      k_gruprep<<<NBK, 256, 0, stream>>>(updb, sf, gruT, gru_bih, gru_bhh,
                                         ns_g, ns_b, wq, qb, posb, sclb, stag);
    }
  }

  k_finalize<<<NBK, 256, 0, stream>>>(sf, at0, posb, sclb, stag, out);
}

// Round 6
// 793.773 us; speedup vs baseline: 1.4709x; 1.0952x over previous
//
#include <hip/hip_runtime.h>
#include <math.h>

#define NB 8
#define NN 1024
#define NK 8
#define ND 256
#define ND2 512
#define NBK 64
#define EPSA 1e-8f
#define LNEPS 1e-5f
#define GSTEP (2.0f/31.0f)

using short8 = __attribute__((ext_vector_type(8))) short;
using short4v = __attribute__((ext_vector_type(4))) short;
using floatx4 = __attribute__((ext_vector_type(4))) float;

__device__ __forceinline__ short f2bf(float f) {
  unsigned u = __builtin_bit_cast(unsigned, f);
  u += 0x7fffu + ((u >> 16) & 1u);
  return (short)(u >> 16);
}

// ---------------- all weight conversions in one launch ----------------
__global__ __launch_bounds__(256) void k_cvt_all(
    const float* __restrict__ w1, const float* __restrict__ w2,
    const float* __restrict__ wk, const float* __restrict__ wv,
    const float* __restrict__ wih, const float* __restrict__ whh,
    short* __restrict__ w1T, short* __restrict__ w2T,
    short* __restrict__ wkT, short* __restrict__ wvT,
    float* __restrict__ gT) {
  const int idx = blockIdx.x * 256 + threadIdx.x;
  if (idx < 131072) {
    const int n = idx >> 8, k = idx & 255;
    w1T[idx] = f2bf(w1[(size_t)k * 512 + n]);
  } else if (idx < 262144) {
    const int i = idx - 131072;
    const int n = i >> 9, k = i & 511;
    w2T[i] = f2bf(w2[(size_t)k * 256 + n]);
  } else if (idx < 327680) {
    const int i = idx - 262144;
    const int n = i >> 8, k = i & 255;
    wkT[i] = f2bf(wk[(size_t)k * 256 + n]);
  } else if (idx < 393216) {
    const int i = idx - 327680;
    const int n = i >> 8, k = i & 255;
    wvT[i] = f2bf(wv[(size_t)k * 256 + n]);
  } else {
    const int i2 = idx - 393216;          // 0..393215
    const float* src = (i2 >= 196608) ? whh : wih;
    const int i3 = (i2 >= 196608) ? (i2 - 196608) : i2;  // 196608 not pow2!
    const int d = i3 / 768, j = i3 % 768;
    gT[i2] = src[(size_t)j * 256 + d];
  }
}

// ---------------- k/v projection via bf16 MFMA (LN stats inline) ----------------
__global__ __launch_bounds__(256, 2) void k_gemm_kv_mfma(
    const float* __restrict__ inp,
    const float* __restrict__ nig, const float* __restrict__ nib,
    const short* __restrict__ wkT, const short* __restrict__ wvT,
    float* __restrict__ kout, float* __restrict__ vout) {
  __shared__ __align__(16) short tln[64 * 264];
  const short* __restrict__ WT = blockIdx.z ? wvT : wkT;
  float* __restrict__ out = blockIdx.z ? vout : kout;
  const int row0 = blockIdx.x * 64;
  const int t = threadIdx.x;
  const int wave = t >> 6, lane = t & 63, l15 = lane & 15, quad = lane >> 4;
  {
    const int r = t >> 2, sub = t & 3;
    const float* xr = inp + (size_t)(row0 + r) * ND;
    float tv[64];
    float sum = 0.f, ssq = 0.f;
#pragma unroll
    for (int ii = 0; ii < 16; ii++) {
      const int d = sub * 4 + ii * 16;
      const float4 xv = *(const float4*)(xr + d);
      tv[ii * 4 + 0] = xv.x; sum += xv.x; ssq += xv.x * xv.x;
      tv[ii * 4 + 1] = xv.y; sum += xv.y; ssq += xv.y * xv.y;
      tv[ii * 4 + 2] = xv.z; sum += xv.z; ssq += xv.z * xv.z;
      tv[ii * 4 + 3] = xv.w; sum += xv.w; ssq += xv.w * xv.w;
    }
    sum += __shfl_xor(sum, 1); ssq += __shfl_xor(ssq, 1);
    sum += __shfl_xor(sum, 2); ssq += __shfl_xor(ssq, 2);
    const float mean = sum * (1.0f / ND);
    const float var = ssq * (1.0f / ND) - mean * mean;
    const float rstd = rsqrtf(var + LNEPS);
#pragma unroll
    for (int ii = 0; ii < 16; ii++) {
      const int d = sub * 4 + ii * 16;
      const float4 gg = *(const float4*)(nig + d);
      const float4 bb = *(const float4*)(nib + d);
      short4v pk;
      pk.x = f2bf((tv[ii * 4 + 0] - mean) * rstd * gg.x + bb.x);
      pk.y = f2bf((tv[ii * 4 + 1] - mean) * rstd * gg.y + bb.y);
      pk.z = f2bf((tv[ii * 4 + 2] - mean) * rstd * gg.z + bb.z);
      pk.w = f2bf((tv[ii * 4 + 3] - mean) * rstd * gg.w + bb.w);
      *(short4v*)&tln[r * 264 + d] = pk;
    }
  }
  __syncthreads();
  floatx4 acc[4][4];
#pragma unroll
  for (int mt = 0; mt < 4; mt++)
#pragma unroll
    for (int nt = 0; nt < 4; nt++) acc[mt][nt] = (floatx4){0.f, 0.f, 0.f, 0.f};
  const short* wp = WT + ((size_t)(wave * 64 + l15)) * 256 + quad * 8;
#pragma unroll
  for (int kk = 0; kk < 8; kk++) {
    short8 af[4];
#pragma unroll
    for (int mt = 0; mt < 4; mt++)
      af[mt] = *(const short8*)&tln[(mt * 16 + l15) * 264 + kk * 32 + quad * 8];
    short8 bf[4];
#pragma unroll
    for (int nt = 0; nt < 4; nt++)
      bf[nt] = *(const short8*)(wp + nt * 16 * 256 + kk * 32);
#pragma unroll
    for (int mt = 0; mt < 4; mt++)
#pragma unroll
      for (int nt = 0; nt < 4; nt++)
        acc[mt][nt] = __builtin_amdgcn_mfma_f32_16x16x32_bf16(af[mt], bf[nt], acc[mt][nt], 0, 0, 0);
  }
#pragma unroll
  for (int mt = 0; mt < 4; mt++)
#pragma unroll
    for (int nt = 0; nt < 4; nt++)
#pragma unroll
      for (int j = 0; j < 4; j++)
        out[(size_t)(row0 + mt * 16 + quad * 4 + j) * ND + wave * 64 + nt * 16 + l15] = acc[mt][nt][j];
}

// ---------------- first prep: pos/scl + q = LN(slots)@wq ; zero upd/stage ----------------
__global__ __launch_bounds__(256) void k_prep(
    const float* __restrict__ sf, const float* __restrict__ nsg,
    const float* __restrict__ nsb, const float* __restrict__ wq,
    float* __restrict__ q, float* __restrict__ pos, float* __restrict__ scl,
    float* __restrict__ upd, float* __restrict__ stage) {
  const int bk = blockIdx.x;
  const int t = threadIdx.x;
  upd[bk * ND + t] = 0.f;
  if (t < 8) stage[bk * 8 + t] = 0.f;
  const float v = sf[bk * 260 + t];
  float s = v, ss = v * v;
#pragma unroll
  for (int m = 32; m >= 1; m >>= 1) { s += __shfl_xor(s, m); ss += __shfl_xor(ss, m); }
  __shared__ float red[8];
  __shared__ float lnv[256];
  const int wv = t >> 6;
  if ((t & 63) == 0) { red[wv] = s; red[4 + wv] = ss; }
  __syncthreads();
  const float S = red[0] + red[1] + red[2] + red[3];
  const float SS = red[4] + red[5] + red[6] + red[7];
  const float mean = S * (1.0f / ND);
  const float var = SS * (1.0f / ND) - mean * mean;
  const float rstd = rsqrtf(var + LNEPS);
  lnv[t] = (v - mean) * rstd * nsg[t] + nsb[t];
  if (t < 2) {
    const float p = sf[bk * 260 + 256 + t];
    pos[bk * 2 + t] = fminf(fmaxf(p, -1.0f), 1.0f);
    const float sc = sf[bk * 260 + 258 + t];
    scl[bk * 2 + t] = fminf(fmaxf(sc, 1e-3f), 2.0f);
  }
  __syncthreads();
  float acc = 0.f;
#pragma unroll 8
  for (int e = 0; e < ND; e++) acc = fmaf(lnv[e], wq[e * ND + t], acc);
  q[bk * ND + t] = acc;
}

// ---------------- fused grid_enc pass: monolithic 64-row (r2 structure) ----------------
// + explicit register double-buffer prefetch of global B-frags and LDS A-frags.
#define LDA 264

__device__ __forceinline__ int h1idx(int row, int col) {
  return (row << 9) + ((((col >> 3) ^ (row & 7)) << 3) | (col & 7));
}

__global__ __launch_bounds__(256, 2) void k_fused_mfma(
    const float* __restrict__ kv,
    const float* __restrict__ pos, const float* __restrict__ scl,
    const float* __restrict__ gpw, const float* __restrict__ gpb,
    const float* __restrict__ lng, const float* __restrict__ lnb,
    const short* __restrict__ w1T, const float* __restrict__ b1,
    const short* __restrict__ w2T, const float* __restrict__ b2,
    const float* __restrict__ q, float* __restrict__ dots,
    const float* __restrict__ attn0, const float* __restrict__ stage,
    float* __restrict__ upd, const int mode) {
  __shared__ __align__(16) short smem[64 * 512];  // 64 KB; tln & h1 & dred alias
  short* tln = smem;
  short* h1 = smem;

  const int bk = blockIdx.y;
  const int n0 = blockIdx.x * 64;
  const int b = bk >> 3;
  const int t = threadIdx.x;
  const int wave = t >> 6;
  const int lane = t & 63;
  const int l15 = lane & 15;
  const int quad = lane >> 4;

  // ---- Phase A: tln = LN(kv + rel_enc) -> bf16 LDS (64 rows, 4 thr/row) ----
  {
    const float p0 = pos[bk * 2 + 0], p1 = pos[bk * 2 + 1];
    const float s0i = 1.0f / (scl[bk * 2 + 0] * 5.0f);
    const float s1i = 1.0f / (scl[bk * 2 + 1] * 5.0f);
    const int r = t >> 2;
    const int sub = t & 3;
    const int n = n0 + r;
    const float gx = -1.0f + GSTEP * (float)(n >> 5);
    const float gy = -1.0f + GSTEP * (float)(n & 31);
    const float rg0 = (gx - p0) * s0i;
    const float rg1 = (gy - p1) * s1i;
    const float* kvrow = kv + (size_t)(b * NN + n) * ND;
    float tv[64];
    float sum = 0.f, ssq = 0.f;
#pragma unroll
    for (int ii = 0; ii < 16; ii++) {
      const int d = sub * 4 + ii * 16;
      const float4 kv4 = *(const float4*)(kvrow + d);
      const float4 wa = *(const float4*)(gpw + d);
      const float4 wb = *(const float4*)(gpw + ND + d);
      const float4 pb = *(const float4*)(gpb + d);
      float v0 = kv4.x + rg0 * wa.x + rg1 * wb.x + pb.x;
      float v1 = kv4.y + rg0 * wa.y + rg1 * wb.y + pb.y;
      float v2 = kv4.z + rg0 * wa.z + rg1 * wb.z + pb.z;
      float v3 = kv4.w + rg0 * wa.w + rg1 * wb.w + pb.w;
      tv[ii * 4 + 0] = v0; sum += v0; ssq += v0 * v0;
      tv[ii * 4 + 1] = v1; sum += v1; ssq += v1 * v1;
      tv[ii * 4 + 2] = v2; sum += v2; ssq += v2 * v2;
      tv[ii * 4 + 3] = v3; sum += v3; ssq += v3 * v3;
    }
    sum += __shfl_xor(sum, 1); ssq += __shfl_xor(ssq, 1);
    sum += __shfl_xor(sum, 2); ssq += __shfl_xor(ssq, 2);
    const float mean = sum * (1.0f / ND);
    const float var = ssq * (1.0f / ND) - mean * mean;
    const float rstd = rsqrtf(var + LNEPS);
#pragma unroll
    for (int ii = 0; ii < 16; ii++) {
      const int d = sub * 4 + ii * 16;
      const float4 gg = *(const float4*)(lng + d);
      const float4 bb = *(const float4*)(lnb + d);
      short4v pk;
      pk.x = f2bf((tv[ii * 4 + 0] - mean) * rstd * gg.x + bb.x);
      pk.y = f2bf((tv[ii * 4 + 1] - mean) * rstd * gg.y + bb.y);
      pk.z = f2bf((tv[ii * 4 + 2] - mean) * rstd * gg.z + bb.z);
      pk.w = f2bf((tv[ii * 4 + 3] - mean) * rstd * gg.w + bb.w);
      *(short4v*)&tln[r * LDA + d] = pk;
    }
  }
  __syncthreads();

  // ---- GEMM1: h1 = relu(tln @ W1T^T + b1). Wave owns 128 cols. Prefetched. ----
  floatx4 acc1[4][8];
#pragma unroll
  for (int mt = 0; mt < 4; mt++)
#pragma unroll
    for (int nt = 0; nt < 8; nt++) acc1[mt][nt] = (floatx4){0.f, 0.f, 0.f, 0.f};

  const short* w1p = w1T + ((size_t)(wave * 128 + l15)) * 256 + quad * 8;
  {
    short8 bcur[8], acur[4];
#pragma unroll
    for (int nt = 0; nt < 8; nt++) bcur[nt] = *(const short8*)(w1p + nt * 16 * 256);
#pragma unroll
    for (int mt = 0; mt < 4; mt++)
      acur[mt] = *(const short8*)&tln[(mt * 16 + l15) * LDA + quad * 8];
#pragma unroll
    for (int kk = 0; kk < 8; kk++) {
      short8 bnxt[8], anxt[4];
      if (kk < 7) {
#pragma unroll
        for (int nt = 0; nt < 8; nt++)
          bnxt[nt] = *(const short8*)(w1p + nt * 16 * 256 + (kk + 1) * 32);
#pragma unroll
        for (int mt = 0; mt < 4; mt++)
          anxt[mt] = *(const short8*)&tln[(mt * 16 + l15) * LDA + (kk + 1) * 32 + quad * 8];
      }
#pragma unroll
      for (int mt = 0; mt < 4; mt++)
#pragma unroll
        for (int nt = 0; nt < 8; nt++)
          acc1[mt][nt] = __builtin_amdgcn_mfma_f32_16x16x32_bf16(acur[mt], bcur[nt], acc1[mt][nt], 0, 0, 0);
      if (kk < 7) {
#pragma unroll
        for (int nt = 0; nt < 8; nt++) bcur[nt] = bnxt[nt];
#pragma unroll
        for (int mt = 0; mt < 4; mt++) acur[mt] = anxt[mt];
      }
    }
  }
  __syncthreads();  // all tln reads done before h1 overwrites

  {
    float b1v[8];
#pragma unroll
    for (int nt = 0; nt < 8; nt++) b1v[nt] = b1[wave * 128 + nt * 16 + l15];
#pragma unroll
    for (int mt = 0; mt < 4; mt++)
#pragma unroll
      for (int nt = 0; nt < 8; nt++) {
        const int col = wave * 128 + nt * 16 + l15;
#pragma unroll
        for (int j = 0; j < 4; j++) {
          const int row = mt * 16 + quad * 4 + j;
          h1[h1idx(row, col)] = f2bf(fmaxf(acc1[mt][nt][j] + b1v[nt], 0.f));
        }
      }
  }
  __syncthreads();

  // ---- GEMM2: o = h1 @ W2T^T (+b2). Wave owns 64 cols. K paired (64/slab), prefetched. ----
  floatx4 acc2[4][4];
#pragma unroll
  for (int mt = 0; mt < 4; mt++)
#pragma unroll
    for (int nt = 0; nt < 4; nt++) acc2[mt][nt] = (floatx4){0.f, 0.f, 0.f, 0.f};

  const short* w2p = w2T + ((size_t)(wave * 64 + l15)) * 512 + quad * 8;
  {
    short8 bcur[8], acur[8];   // [i*4+nt] / [i*4+mt] for kk = 2*kp+i
#pragma unroll
    for (int i = 0; i < 2; i++) {
#pragma unroll
      for (int nt = 0; nt < 4; nt++)
        bcur[i * 4 + nt] = *(const short8*)(w2p + nt * 16 * 512 + i * 32);
#pragma unroll
      for (int mt = 0; mt < 4; mt++) {
        const int row = mt * 16 + l15;
        acur[i * 4 + mt] = *(const short8*)&h1[(row << 9) + (((i * 4 + quad) ^ (row & 7)) << 3)];
      }
    }
#pragma unroll
    for (int kp = 0; kp < 8; kp++) {
      short8 bnxt[8], anxt[8];
      if (kp < 7) {
#pragma unroll
        for (int i = 0; i < 2; i++) {
          const int kk = 2 * (kp + 1) + i;
#pragma unroll
          for (int nt = 0; nt < 4; nt++)
            bnxt[i * 4 + nt] = *(const short8*)(w2p + nt * 16 * 512 + kk * 32);
#pragma unroll
          for (int mt = 0; mt < 4; mt++) {
            const int row = mt * 16 + l15;
            anxt[i * 4 + mt] = *(const short8*)&h1[(row << 9) + (((kk * 4 + quad) ^ (row & 7)) << 3)];
          }
        }
      }
#pragma unroll
      for (int i = 0; i < 2; i++)
#pragma unroll
        for (int mt = 0; mt < 4; mt++)
#pragma unroll
          for (int nt = 0; nt < 4; nt++)
            acc2[mt][nt] = __builtin_amdgcn_mfma_f32_16x16x32_bf16(acur[i * 4 + mt], bcur[i * 4 + nt], acc2[mt][nt], 0, 0, 0);
      if (kp < 7) {
#pragma unroll
        for (int x = 0; x < 8; x++) { bcur[x] = bnxt[x]; acur[x] = anxt[x]; }
      }
    }
  }

  float b2v[4];
#pragma unroll
  for (int nt = 0; nt < 4; nt++) b2v[nt] = b2[wave * 64 + nt * 16 + l15];

  if (mode == 0) {
    float qn[4];
#pragma unroll
    for (int nt = 0; nt < 4; nt++) qn[nt] = q[bk * ND + wave * 64 + nt * 16 + l15];
    __syncthreads();  // done reading h1; reuse smem as float dred[4][64]
    float* dred = (float*)smem;
#pragma unroll
    for (int mt = 0; mt < 4; mt++)
#pragma unroll
      for (int j = 0; j < 4; j++) {
        float p = 0.f;
#pragma unroll
        for (int nt = 0; nt < 4; nt++)
          p = fmaf(acc2[mt][nt][j] + b2v[nt], qn[nt], p);
        p += __shfl_xor(p, 1); p += __shfl_xor(p, 2);
        p += __shfl_xor(p, 4); p += __shfl_xor(p, 8);
        if (l15 == 0) dred[wave * 64 + mt * 16 + quad * 4 + j] = p;
      }
    __syncthreads();
    if (t < 64) {
      const float s = dred[t] + dred[64 + t] + dred[128 + t] + dred[192 + t];
      dots[bk * NN + n0 + t] = s * 0.0625f;
    }
  } else {
    const float dn = 1.0f / (stage[bk * 8 + 0] + (float)NN * EPSA);
    float aw[4][4];
#pragma unroll
    for (int mt = 0; mt < 4; mt++)
#pragma unroll
      for (int j = 0; j < 4; j++)
        aw[mt][j] = (attn0[bk * NN + n0 + mt * 16 + quad * 4 + j] + EPSA) * dn;
#pragma unroll
    for (int nt = 0; nt < 4; nt++) {
      float s = 0.f;
#pragma unroll
      for (int mt = 0; mt < 4; mt++)
#pragma unroll
        for (int j = 0; j < 4; j++)
          s = fmaf(aw[mt][j], acc2[mt][nt][j] + b2v[nt], s);
      s += __shfl_xor(s, 16); s += __shfl_xor(s, 32);
      if (quad == 0) atomicAdd(upd + bk * ND + wave * 64 + nt * 16 + l15, s);
    }
  }
}

// ---------------- softmax over K + one-pass moment sums -> stage ----------------
__global__ __launch_bounds__(256) void k_softmax_reduce(
    const float* __restrict__ dots, float* __restrict__ attn0,
    float* __restrict__ stage) {
  const int t = threadIdx.x;
  const int idx = blockIdx.x * 256 + t;
  const int b = idx >> 10, n = idx & 1023;
  const int lane = t & 63, wave = t >> 6;
  float vals[NK];
  float mx = -1e30f;
#pragma unroll
  for (int k = 0; k < NK; k++) {
    vals[k] = dots[(size_t)(b * NK + k) * NN + n];
    mx = fmaxf(mx, vals[k]);
  }
  float s = 0.f;
#pragma unroll
  for (int k = 0; k < NK; k++) { vals[k] = expf(vals[k] - mx); s += vals[k]; }
  const float inv = 1.0f / s;
  const float gx = -1.0f + GSTEP * (float)(n >> 5);
  const float gy = -1.0f + GSTEP * (float)(n & 31);
  const float gx2 = gx * gx, gy2 = gy * gy;
  float sk[NK][5];
#pragma unroll
  for (int k = 0; k < NK; k++) {
    const float a = vals[k] * inv;
    attn0[(size_t)(b * NK + k) * NN + n] = a;
    const float w = a + EPSA;
    sk[k][0] = a;
    sk[k][1] = a * gx;
    sk[k][2] = a * gy;
    sk[k][3] = w * gx2;
    sk[k][4] = w * gy2;
  }
#pragma unroll
  for (int m = 32; m >= 1; m >>= 1)
#pragma unroll
    for (int k = 0; k < NK; k++)
#pragma unroll
      for (int c = 0; c < 5; c++)
        sk[k][c] += __shfl_xor(sk[k][c], m);
  __shared__ float red[4][40];
  if (lane == 0) {
#pragma unroll
    for (int k = 0; k < NK; k++)
#pragma unroll
      for (int c = 0; c < 5; c++)
        red[wave][k * 5 + c] = sk[k][c];
  }
  __syncthreads();
  if (t < 40) {
    const float tot = red[0][t] + red[1][t] + red[2][t] + red[3][t];
    const int k = t / 5, c = t % 5;
    atomicAdd(&stage[(b * NK + k) * 8 + c], tot);
  }
}

// ---------------- GRU + next-iter prep (merged) ----------------
__global__ __launch_bounds__(256) void k_gruprep(
    float* __restrict__ upd, float* __restrict__ sf,
    const float* __restrict__ gT,
    const float* __restrict__ bih, const float* __restrict__ bhh,
    const float* __restrict__ nsg, const float* __restrict__ nsb,
    const float* __restrict__ wq,
    float* __restrict__ q, float* __restrict__ pos, float* __restrict__ scl,
    float* __restrict__ stage) {
  const int bk = blockIdx.x, t = threadIdx.x;
  __shared__ float u[256], h[256], lnv[256], red[8];
  u[t] = upd[bk * ND + t];
  h[t] = sf[bk * 260 + t];
  __syncthreads();
  const float* wi = gT;             // [256][768]
  const float* wh = gT + 196608;    // [256][768]
  float a0 = 0.f, a1 = 0.f, a2 = 0.f, c0 = 0.f, c1 = 0.f, c2 = 0.f;
#pragma unroll 4
  for (int d = 0; d < ND; d++) {
    const float ud = u[d], hd = h[d];
    const float* wid = wi + (size_t)d * 768;
    const float* whd = wh + (size_t)d * 768;
    a0 = fmaf(ud, wid[t], a0);
    a1 = fmaf(ud, wid[256 + t], a1);
    a2 = fmaf(ud, wid[512 + t], a2);
    c0 = fmaf(hd, whd[t], c0);
    c1 = fmaf(hd, whd[256 + t], c1);
    c2 = fmaf(hd, whd[512 + t], c2);
  }
  const float r = 1.0f / (1.0f + expf(-(a0 + bih[t] + c0 + bhh[t])));
  const float z = 1.0f / (1.0f + expf(-(a1 + bih[256 + t] + c1 + bhh[256 + t])));
  const float nw = tanhf(a2 + bih[512 + t] + r * (c2 + bhh[512 + t]));
  const float ns = (1.0f - z) * nw + z * h[t];
  sf[bk * 260 + t] = ns;
  float s2 = ns, ss = ns * ns;
#pragma unroll
  for (int m = 32; m >= 1; m >>= 1) { s2 += __shfl_xor(s2, m); ss += __shfl_xor(ss, m); }
  const int wv = t >> 6;
  if ((t & 63) == 0) { red[wv] = s2; red[4 + wv] = ss; }
  __syncthreads();
  const float S = red[0] + red[1] + red[2] + red[3];
  const float SS = red[4] + red[5] + red[6] + red[7];
  const float mean = S * (1.0f / ND);
  const float var = SS * (1.0f / ND) - mean * mean;
  const float rstd = rsqrtf(var + LNEPS);
  lnv[t] = (ns - mean) * rstd * nsg[t] + nsb[t];
  __syncthreads();
  float acc = 0.f;
#pragma unroll 8
  for (int e = 0; e < ND; e++) acc = fmaf(lnv[e], wq[e * ND + t], acc);
  q[bk * ND + t] = acc;
  if (t == 0) {
    const float Sa = stage[bk * 8 + 0];
    const float G0 = stage[bk * 8 + 1];
    const float G1 = stage[bk * 8 + 2];
    const float Q0 = stage[bk * 8 + 3];
    const float Q1 = stage[bk * 8 + 4];
    const float W = Sa + (float)NN * EPSA;
    const float sc0 = sqrtf(fmaxf(Q0 - 2.0f * G0 * G0 + G0 * G0 * W, 0.f));
    const float sc1 = sqrtf(fmaxf(Q1 - 2.0f * G1 * G1 + G1 * G1 * W, 0.f));
    const float sc0c = fminf(fmaxf(sc0, 1e-3f), 2.0f);
    const float sc1c = fminf(fmaxf(sc1, 1e-3f), 2.0f);
    sf[bk * 260 + 256] = G0;
    sf[bk * 260 + 257] = G1;
    sf[bk * 260 + 258] = sc0c;
    sf[bk * 260 + 259] = sc1c;
    pos[bk * 2 + 0] = fminf(fmaxf(G0, -1.0f), 1.0f);
    pos[bk * 2 + 1] = fminf(fmaxf(G1, -1.0f), 1.0f);
    scl[bk * 2 + 0] = sc0c;
    scl[bk * 2 + 1] = sc1c;
  }
  __syncthreads();
  if (t < 8) stage[bk * 8 + t] = 0.f;
  upd[bk * ND + t] = 0.f;
}

// ---------------- finalize ----------------
__global__ __launch_bounds__(256) void k_finalize(
    const float* __restrict__ sf, const float* __restrict__ attn0,
    const float* __restrict__ pos, const float* __restrict__ scl,
    const float* __restrict__ stage, float* __restrict__ out) {
  const int bk = blockIdx.x, t = threadIdx.x;
  out[bk * 260 + t] = sf[bk * 260 + t];
  if (t == 0) {
    const float Sa = stage[bk * 8 + 0];
    const float G0 = stage[bk * 8 + 1];
    const float G1 = stage[bk * 8 + 2];
    const float Q0 = stage[bk * 8 + 3];
    const float Q1 = stage[bk * 8 + 4];
    const float W = Sa + (float)NN * EPSA;
    const float sc0 = sqrtf(fmaxf(Q0 - 2.0f * G0 * G0 + G0 * G0 * W, 0.f));
    const float sc1 = sqrtf(fmaxf(Q1 - 2.0f * G1 * G1 + G1 * G1 * W, 0.f));
    out[bk * 260 + 256] = G0;
    out[bk * 260 + 257] = G1;
    out[bk * 260 + 258] = fminf(fmaxf(sc0, 1e-3f), 2.0f);
    out[bk * 260 + 259] = fminf(fmaxf(sc1, 1e-3f), 2.0f);
  }
  const float p0 = pos[bk * 2 + 0], p1 = pos[bk * 2 + 1];
  const float s0 = scl[bk * 2 + 0] * 5.0f, s1 = scl[bk * 2 + 1] * 5.0f;
#pragma unroll
  for (int i = 0; i < 4; i++) {
    const int n = t + 256 * i;
    out[16640 + bk * NN + n] = attn0[(size_t)bk * NN + n];
    const float gx = -1.0f + GSTEP * (float)(n >> 5);
    const float gy = -1.0f + GSTEP * (float)(n & 31);
    float2 v;
    v.x = (gx - p0) / s0;
    v.y = (gy - p1) / s1;
    *(float2*)(out + 16640 + 65536 + ((size_t)bk * NN + n) * 2) = v;
  }
}

extern "C" void kernel_launch(void* const* d_in, const int* in_sizes, int n_in,
                              void* d_out, int out_size, void* d_ws, size_t ws_size,
                              hipStream_t stream) {
  const float* inputs   = (const float*)d_in[0];
  const float* cond     = (const float*)d_in[1];
  const float* ni_g     = (const float*)d_in[2];
  const float* ni_b     = (const float*)d_in[3];
  const float* ns_g     = (const float*)d_in[4];
  const float* ns_b     = (const float*)d_in[5];
  const float* wq       = (const float*)d_in[6];
  const float* wk       = (const float*)d_in[7];
  const float* wv       = (const float*)d_in[8];
  const float* gp_w     = (const float*)d_in[9];
  const float* gp_b     = (const float*)d_in[10];
  const float* ge_ln_g  = (const float*)d_in[11];
  const float* ge_ln_b  = (const float*)d_in[12];
  const float* ge_w1    = (const float*)d_in[13];
  const float* ge_b1    = (const float*)d_in[14];
  const float* ge_w2    = (const float*)d_in[15];
  const float* ge_b2    = (const float*)d_in[16];
  const float* gru_wih  = (const float*)d_in[17];
  const float* gru_whh  = (const float*)d_in[18];
  const float* gru_bih  = (const float*)d_in[19];
  const float* gru_bhh  = (const float*)d_in[20];

  float* ws   = (float*)d_ws;
  float* kbuf = ws;                  // 8*1024*256
  float* vbuf = kbuf + 2097152;      // 8*1024*256
  float* sf   = vbuf + 2097152;      // 64*260
  float* qb   = sf + 16640;          // 64*256
  float* posb = qb + 16384;          // 64*2 (padded)
  float* sclb = posb + 128;          // 64*2 (padded)
  float* dotsb = sclb + 128;         // 64*1024
  float* at0  = dotsb + 65536;       // 64*1024
  float* updb = at0 + 65536;         // 64*256
  float* stag = updb + 16384;        // 64*8
  float* gruT = stag + 512;          // 2*256*768
  short* w1T  = (short*)(gruT + 393216);  // 512*256 bf16
  short* w2T  = w1T + 131072;             // 256*512 bf16
  short* wkT  = w2T + 131072;             // 256*256 bf16
  short* wvT  = wkT + 65536;              // 256*256 bf16

  float* out = (float*)d_out;

  hipMemcpyAsync(sf, cond, 16640 * sizeof(float), hipMemcpyDeviceToDevice, stream);

  k_cvt_all<<<3072, 256, 0, stream>>>(ge_w1, ge_w2, wk, wv, gru_wih, gru_whh,
                                      w1T, w2T, wkT, wvT, gruT);
  k_gemm_kv_mfma<<<dim3(128, 1, 2), 256, 0, stream>>>(inputs, ni_g, ni_b,
                                                      wkT, wvT, kbuf, vbuf);
  k_prep<<<NBK, 256, 0, stream>>>(sf, ns_g, ns_b, wq, qb, posb, sclb, updb, stag);

  for (int s = 0; s < 4; s++) {
    k_fused_mfma<<<dim3(16, NBK), 256, 0, stream>>>(
        kbuf, posb, sclb, gp_w, gp_b, ge_ln_g, ge_ln_b, w1T, ge_b1, w2T, ge_b2,
        qb, dotsb, at0, stag, updb, 0);
    k_softmax_reduce<<<32, 256, 0, stream>>>(dotsb, at0, stag);
    if (s < 3) {
      k_fused_mfma<<<dim3(16, NBK), 256, 0, stream>>>(
          vbuf, posb, sclb, gp_w, gp_b, ge_ln_g, ge_ln_b, w1T, ge_b1, w2T, ge_b2,
          qb, dotsb, at0, stag, updb, 1);
      k_gruprep<<<NBK, 256, 0, stream>>>(updb, sf, gruT, gru_bih, gru_bhh,
                                         ns_g, ns_b, wq, qb, posb, sclb, stag);
    }
  }

  k_finalize<<<NBK, 256, 0, stream>>>(sf, at0, posb, sclb, stag, out);
}

// Round 7
// 724.190 us; speedup vs baseline: 1.6122x; 1.0961x over previous
//
#include <hip/hip_runtime.h>
#include <math.h>

#define NB 8
#define NN 1024
#define NK 8
#define ND 256
#define ND2 512
#define NBK 64
#define EPSA 1e-8f
#define LNEPS 1e-5f
#define GSTEP (2.0f/31.0f)

using short8 = __attribute__((ext_vector_type(8))) short;
using short4v = __attribute__((ext_vector_type(4))) short;
using floatx4 = __attribute__((ext_vector_type(4))) float;

__device__ __forceinline__ short f2bf(float f) {
  unsigned u = __builtin_bit_cast(unsigned, f);
  u += 0x7fffu + ((u >> 16) & 1u);
  return (short)(u >> 16);
}
__device__ __forceinline__ float bf2f(short s) {
  unsigned u = ((unsigned)(unsigned short)s) << 16;
  return __builtin_bit_cast(float, u);
}

// ---------------- all weight conversions in one launch ----------------
__global__ __launch_bounds__(256) void k_cvt_all(
    const float* __restrict__ w1, const float* __restrict__ w2,
    const float* __restrict__ wk, const float* __restrict__ wv,
    const float* __restrict__ wih, const float* __restrict__ whh,
    short* __restrict__ w1T, short* __restrict__ w2T,
    short* __restrict__ wkT, short* __restrict__ wvT,
    float* __restrict__ gT) {
  const int idx = blockIdx.x * 256 + threadIdx.x;
  if (idx < 131072) {
    const int n = idx >> 8, k = idx & 255;
    w1T[idx] = f2bf(w1[(size_t)k * 512 + n]);
  } else if (idx < 262144) {
    const int i = idx - 131072;
    const int n = i >> 9, k = i & 511;
    w2T[i] = f2bf(w2[(size_t)k * 256 + n]);    // w2T[d][j] = ge_w2[j][d]
  } else if (idx < 327680) {
    const int i = idx - 262144;
    const int n = i >> 8, k = i & 255;
    wkT[i] = f2bf(wk[(size_t)k * 256 + n]);
  } else if (idx < 393216) {
    const int i = idx - 327680;
    const int n = i >> 8, k = i & 255;
    wvT[i] = f2bf(wv[(size_t)k * 256 + n]);
  } else {
    const int i2 = idx - 393216;          // 0..393215
    const float* src = (i2 >= 196608) ? whh : wih;
    const int i3 = (i2 >= 196608) ? (i2 - 196608) : i2;  // 196608 not pow2!
    const int d = i3 / 768, j = i3 % 768;
    gT[i2] = src[(size_t)j * 256 + d];
  }
}

// ---------------- k/v projection via bf16 MFMA (LN stats inline) ----------------
__global__ __launch_bounds__(256, 2) void k_gemm_kv_mfma(
    const float* __restrict__ inp,
    const float* __restrict__ nig, const float* __restrict__ nib,
    const short* __restrict__ wkT, const short* __restrict__ wvT,
    float* __restrict__ kout, float* __restrict__ vout) {
  __shared__ __align__(16) short tln[64 * 264];
  const short* __restrict__ WT = blockIdx.z ? wvT : wkT;
  float* __restrict__ out = blockIdx.z ? vout : kout;
  const int row0 = blockIdx.x * 64;
  const int t = threadIdx.x;
  const int wave = t >> 6, lane = t & 63, l15 = lane & 15, quad = lane >> 4;
  {
    const int r = t >> 2, sub = t & 3;
    const float* xr = inp + (size_t)(row0 + r) * ND;
    float tv[64];
    float sum = 0.f, ssq = 0.f;
#pragma unroll
    for (int ii = 0; ii < 16; ii++) {
      const int d = sub * 4 + ii * 16;
      const float4 xv = *(const float4*)(xr + d);
      tv[ii * 4 + 0] = xv.x; sum += xv.x; ssq += xv.x * xv.x;
      tv[ii * 4 + 1] = xv.y; sum += xv.y; ssq += xv.y * xv.y;
      tv[ii * 4 + 2] = xv.z; sum += xv.z; ssq += xv.z * xv.z;
      tv[ii * 4 + 3] = xv.w; sum += xv.w; ssq += xv.w * xv.w;
    }
    sum += __shfl_xor(sum, 1); ssq += __shfl_xor(ssq, 1);
    sum += __shfl_xor(sum, 2); ssq += __shfl_xor(ssq, 2);
    const float mean = sum * (1.0f / ND);
    const float var = ssq * (1.0f / ND) - mean * mean;
    const float rstd = rsqrtf(var + LNEPS);
#pragma unroll
    for (int ii = 0; ii < 16; ii++) {
      const int d = sub * 4 + ii * 16;
      const float4 gg = *(const float4*)(nig + d);
      const float4 bb = *(const float4*)(nib + d);
      short4v pk;
      pk.x = f2bf((tv[ii * 4 + 0] - mean) * rstd * gg.x + bb.x);
      pk.y = f2bf((tv[ii * 4 + 1] - mean) * rstd * gg.y + bb.y);
      pk.z = f2bf((tv[ii * 4 + 2] - mean) * rstd * gg.z + bb.z);
      pk.w = f2bf((tv[ii * 4 + 3] - mean) * rstd * gg.w + bb.w);
      *(short4v*)&tln[r * 264 + d] = pk;
    }
  }
  __syncthreads();
  floatx4 acc[4][4];
#pragma unroll
  for (int mt = 0; mt < 4; mt++)
#pragma unroll
    for (int nt = 0; nt < 4; nt++) acc[mt][nt] = (floatx4){0.f, 0.f, 0.f, 0.f};
  const short* wp = WT + ((size_t)(wave * 64 + l15)) * 256 + quad * 8;
#pragma unroll
  for (int kk = 0; kk < 8; kk++) {
    short8 af[4];
#pragma unroll
    for (int mt = 0; mt < 4; mt++)
      af[mt] = *(const short8*)&tln[(mt * 16 + l15) * 264 + kk * 32 + quad * 8];
    short8 bf[4];
#pragma unroll
    for (int nt = 0; nt < 4; nt++)
      bf[nt] = *(const short8*)(wp + nt * 16 * 256 + kk * 32);
#pragma unroll
    for (int mt = 0; mt < 4; mt++)
#pragma unroll
      for (int nt = 0; nt < 4; nt++)
        acc[mt][nt] = __builtin_amdgcn_mfma_f32_16x16x32_bf16(af[mt], bf[nt], acc[mt][nt], 0, 0, 0);
  }
#pragma unroll
  for (int mt = 0; mt < 4; mt++)
#pragma unroll
    for (int nt = 0; nt < 4; nt++)
#pragma unroll
      for (int j = 0; j < 4; j++)
        out[(size_t)(row0 + mt * 16 + quad * 4 + j) * ND + wave * 64 + nt * 16 + l15] = acc[mt][nt][j];
}

// ---------------- first prep: pos/scl + q + w2q + qb2 ; zero ph/stage ----------------
__global__ __launch_bounds__(256) void k_prep(
    const float* __restrict__ sf, const float* __restrict__ nsg,
    const float* __restrict__ nsb, const float* __restrict__ wq,
    const short* __restrict__ w2T, const float* __restrict__ b2,
    float* __restrict__ w2q, float* __restrict__ pos, float* __restrict__ scl,
    float* __restrict__ ph, float* __restrict__ stage) {
  const int bk = blockIdx.x;
  const int t = threadIdx.x;
  ph[bk * 512 + t] = 0.f;
  ph[bk * 512 + 256 + t] = 0.f;
  if (t < 8) stage[bk * 8 + t] = 0.f;
  const float v = sf[bk * 260 + t];
  float s = v, ss = v * v;
#pragma unroll
  for (int m = 32; m >= 1; m >>= 1) { s += __shfl_xor(s, m); ss += __shfl_xor(ss, m); }
  __shared__ float red[8];
  __shared__ float lnv[256];
  __shared__ float qs[256];
  const int wv = t >> 6;
  if ((t & 63) == 0) { red[wv] = s; red[4 + wv] = ss; }
  __syncthreads();
  const float S = red[0] + red[1] + red[2] + red[3];
  const float SS = red[4] + red[5] + red[6] + red[7];
  const float mean = S * (1.0f / ND);
  const float var = SS * (1.0f / ND) - mean * mean;
  const float rstd = rsqrtf(var + LNEPS);
  lnv[t] = (v - mean) * rstd * nsg[t] + nsb[t];
  if (t < 2) {
    const float p = sf[bk * 260 + 256 + t];
    pos[bk * 2 + t] = fminf(fmaxf(p, -1.0f), 1.0f);
    const float sc = sf[bk * 260 + 258 + t];
    scl[bk * 2 + t] = fminf(fmaxf(sc, 1e-3f), 2.0f);
  }
  __syncthreads();
  float qt = 0.f;
#pragma unroll 8
  for (int e = 0; e < ND; e++) qt = fmaf(lnv[e], wq[e * ND + t], qt);
  qs[t] = qt;
  // qb2 = sum b2*q
  float qb = b2[t] * qt;
#pragma unroll
  for (int m = 32; m >= 1; m >>= 1) qb += __shfl_xor(qb, m);
  if ((t & 63) == 0) red[wv] = qb;
  __syncthreads();
  // w2q[j] = sum_d q[d] * w2T[d][j]
  float w0 = 0.f, w1v = 0.f;
#pragma unroll 4
  for (int d = 0; d < ND; d++) {
    const float qd = qs[d];
    w0 = fmaf(qd, bf2f(w2T[d * 512 + t]), w0);
    w1v = fmaf(qd, bf2f(w2T[d * 512 + 256 + t]), w1v);
  }
  w2q[bk * 512 + t] = w0;
  w2q[bk * 512 + 256 + t] = w1v;
  if (t == 0) stage[bk * 8 + 5] = red[0] + red[1] + red[2] + red[3];
}

// ---------------- fused grid_enc pass: GEMM1 only (W2 folded out) ----------------
#define LDA 264

__global__ __launch_bounds__(256, 2) void k_fused_mfma(
    const float* __restrict__ kv,
    const float* __restrict__ pos, const float* __restrict__ scl,
    const float* __restrict__ gpw, const float* __restrict__ gpb,
    const float* __restrict__ lng, const float* __restrict__ lnb,
    const short* __restrict__ w1T, const float* __restrict__ b1,
    const float* __restrict__ w2q, float* __restrict__ dots,
    const float* __restrict__ attn0, const float* __restrict__ stage,
    float* __restrict__ ph, const int mode) {
  __shared__ __align__(16) short tln[64 * LDA];  // 33 KB; dred aliases after barrier

  const int bk = blockIdx.y;
  const int n0 = blockIdx.x * 64;
  const int b = bk >> 3;
  const int t = threadIdx.x;
  const int wave = t >> 6;
  const int lane = t & 63;
  const int l15 = lane & 15;
  const int quad = lane >> 4;

  // ---- Phase A: tln = LN(kv + rel_enc) -> bf16 LDS (64 rows, 4 thr/row) ----
  {
    const float p0 = pos[bk * 2 + 0], p1 = pos[bk * 2 + 1];
    const float s0i = 1.0f / (scl[bk * 2 + 0] * 5.0f);
    const float s1i = 1.0f / (scl[bk * 2 + 1] * 5.0f);
    const int r = t >> 2;
    const int sub = t & 3;
    const int n = n0 + r;
    const float gx = -1.0f + GSTEP * (float)(n >> 5);
    const float gy = -1.0f + GSTEP * (float)(n & 31);
    const float rg0 = (gx - p0) * s0i;
    const float rg1 = (gy - p1) * s1i;
    const float* kvrow = kv + (size_t)(b * NN + n) * ND;
    float tv[64];
    float sum = 0.f, ssq = 0.f;
#pragma unroll
    for (int ii = 0; ii < 16; ii++) {
      const int d = sub * 4 + ii * 16;
      const float4 kv4 = *(const float4*)(kvrow + d);
      const float4 wa = *(const float4*)(gpw + d);
      const float4 wb = *(const float4*)(gpw + ND + d);
      const float4 pb = *(const float4*)(gpb + d);
      float v0 = kv4.x + rg0 * wa.x + rg1 * wb.x + pb.x;
      float v1 = kv4.y + rg0 * wa.y + rg1 * wb.y + pb.y;
      float v2 = kv4.z + rg0 * wa.z + rg1 * wb.z + pb.z;
      float v3 = kv4.w + rg0 * wa.w + rg1 * wb.w + pb.w;
      tv[ii * 4 + 0] = v0; sum += v0; ssq += v0 * v0;
      tv[ii * 4 + 1] = v1; sum += v1; ssq += v1 * v1;
      tv[ii * 4 + 2] = v2; sum += v2; ssq += v2 * v2;
      tv[ii * 4 + 3] = v3; sum += v3; ssq += v3 * v3;
    }
    sum += __shfl_xor(sum, 1); ssq += __shfl_xor(ssq, 1);
    sum += __shfl_xor(sum, 2); ssq += __shfl_xor(ssq, 2);
    const float mean = sum * (1.0f / ND);
    const float var = ssq * (1.0f / ND) - mean * mean;
    const float rstd = rsqrtf(var + LNEPS);
#pragma unroll
    for (int ii = 0; ii < 16; ii++) {
      const int d = sub * 4 + ii * 16;
      const float4 gg = *(const float4*)(lng + d);
      const float4 bb = *(const float4*)(lnb + d);
      short4v pk;
      pk.x = f2bf((tv[ii * 4 + 0] - mean) * rstd * gg.x + bb.x);
      pk.y = f2bf((tv[ii * 4 + 1] - mean) * rstd * gg.y + bb.y);
      pk.z = f2bf((tv[ii * 4 + 2] - mean) * rstd * gg.z + bb.z);
      pk.w = f2bf((tv[ii * 4 + 3] - mean) * rstd * gg.w + bb.w);
      *(short4v*)&tln[r * LDA + d] = pk;
    }
  }
  __syncthreads();

  // ---- GEMM1: h1 = tln @ W1T^T (relu+bias in epilogue). Wave owns 128 cols. ----
  floatx4 acc1[4][8];
#pragma unroll
  for (int mt = 0; mt < 4; mt++)
#pragma unroll
    for (int nt = 0; nt < 8; nt++) acc1[mt][nt] = (floatx4){0.f, 0.f, 0.f, 0.f};

  const short* w1p = w1T + ((size_t)(wave * 128 + l15)) * 256 + quad * 8;
#pragma unroll
  for (int kk = 0; kk < 8; kk++) {
    short8 af[4];
#pragma unroll
    for (int mt = 0; mt < 4; mt++)
      af[mt] = *(const short8*)&tln[(mt * 16 + l15) * LDA + kk * 32 + quad * 8];
    short8 bf[8];
#pragma unroll
    for (int nt = 0; nt < 8; nt++)
      bf[nt] = *(const short8*)(w1p + nt * 16 * 256 + kk * 32);
#pragma unroll
    for (int mt = 0; mt < 4; mt++)
#pragma unroll
      for (int nt = 0; nt < 8; nt++)
        acc1[mt][nt] = __builtin_amdgcn_mfma_f32_16x16x32_bf16(af[mt], bf[nt], acc1[mt][nt], 0, 0, 0);
  }

  float b1v[8];
#pragma unroll
  for (int nt = 0; nt < 8; nt++) b1v[nt] = b1[wave * 128 + nt * 16 + l15];

  if (mode == 0) {
    // dots[n] = sum_j relu(h1[n,j]) * w2q[j] + qb2, * 1/16
    float w2qv[8];
#pragma unroll
    for (int nt = 0; nt < 8; nt++) w2qv[nt] = w2q[bk * 512 + wave * 128 + nt * 16 + l15];
    const float qb2 = stage[bk * 8 + 5];
    __syncthreads();  // all tln reads done; alias as dred
    float* dred = (float*)tln;
#pragma unroll
    for (int mt = 0; mt < 4; mt++)
#pragma unroll
      for (int j = 0; j < 4; j++) {
        float p = 0.f;
#pragma unroll
        for (int nt = 0; nt < 8; nt++)
          p = fmaf(fmaxf(acc1[mt][nt][j] + b1v[nt], 0.f), w2qv[nt], p);
        p += __shfl_xor(p, 1); p += __shfl_xor(p, 2);
        p += __shfl_xor(p, 4); p += __shfl_xor(p, 8);
        if (l15 == 0) dred[wave * 64 + mt * 16 + quad * 4 + j] = p;
      }
    __syncthreads();
    if (t < 64) {
      const float s = dred[t] + dred[64 + t] + dred[128 + t] + dred[192 + t];
      dots[bk * NN + n0 + t] = (s + qb2) * 0.0625f;
    }
  } else {
    // ph[j] += sum_n attn[n] * relu(h1[n,j])
    const float dn = 1.0f / (stage[bk * 8 + 0] + (float)NN * EPSA);
    float aw[4][4];
#pragma unroll
    for (int mt = 0; mt < 4; mt++)
#pragma unroll
      for (int j = 0; j < 4; j++)
        aw[mt][j] = (attn0[bk * NN + n0 + mt * 16 + quad * 4 + j] + EPSA) * dn;
#pragma unroll
    for (int nt = 0; nt < 8; nt++) {
      float cs = 0.f;
#pragma unroll
      for (int mt = 0; mt < 4; mt++)
#pragma unroll
        for (int j = 0; j < 4; j++)
          cs = fmaf(aw[mt][j], fmaxf(acc1[mt][nt][j] + b1v[nt], 0.f), cs);
      cs += __shfl_xor(cs, 16); cs += __shfl_xor(cs, 32);
      if (quad == 0) atomicAdd(ph + bk * 512 + wave * 128 + nt * 16 + l15, cs);
    }
  }
}

// ---------------- softmax over K + one-pass moment sums -> stage ----------------
__global__ __launch_bounds__(256) void k_softmax_reduce(
    const float* __restrict__ dots, float* __restrict__ attn0,
    float* __restrict__ stage) {
  const int t = threadIdx.x;
  const int idx = blockIdx.x * 256 + t;
  const int b = idx >> 10, n = idx & 1023;
  const int lane = t & 63, wave = t >> 6;
  float vals[NK];
  float mx = -1e30f;
#pragma unroll
  for (int k = 0; k < NK; k++) {
    vals[k] = dots[(size_t)(b * NK + k) * NN + n];
    mx = fmaxf(mx, vals[k]);
  }
  float s = 0.f;
#pragma unroll
  for (int k = 0; k < NK; k++) { vals[k] = expf(vals[k] - mx); s += vals[k]; }
  const float inv = 1.0f / s;
  const float gx = -1.0f + GSTEP * (float)(n >> 5);
  const float gy = -1.0f + GSTEP * (float)(n & 31);
  const float gx2 = gx * gx, gy2 = gy * gy;
  float sk[NK][5];
#pragma unroll
  for (int k = 0; k < NK; k++) {
    const float a = vals[k] * inv;
    attn0[(size_t)(b * NK + k) * NN + n] = a;
    const float w = a + EPSA;
    sk[k][0] = a;
    sk[k][1] = a * gx;
    sk[k][2] = a * gy;
    sk[k][3] = w * gx2;
    sk[k][4] = w * gy2;
  }
#pragma unroll
  for (int m = 32; m >= 1; m >>= 1)
#pragma unroll
    for (int k = 0; k < NK; k++)
#pragma unroll
      for (int c = 0; c < 5; c++)
        sk[k][c] += __shfl_xor(sk[k][c], m);
  __shared__ float red[4][40];
  if (lane == 0) {
#pragma unroll
    for (int k = 0; k < NK; k++)
#pragma unroll
      for (int c = 0; c < 5; c++)
        red[wave][k * 5 + c] = sk[k][c];
  }
  __syncthreads();
  if (t < 40) {
    const float tot = red[0][t] + red[1][t] + red[2][t] + red[3][t];
    const int k = t / 5, c = t % 5;
    atomicAdd(&stage[(b * NK + k) * 8 + c], tot);
  }
}

// ---------------- GRU + next-iter prep (merged; includes ph@W2 and w2q) ----------------
__global__ __launch_bounds__(256) void k_gruprep(
    float* __restrict__ ph, float* __restrict__ sf,
    const float* __restrict__ gT,
    const float* __restrict__ bih, const float* __restrict__ bhh,
    const float* __restrict__ nsg, const float* __restrict__ nsb,
    const float* __restrict__ wq,
    const short* __restrict__ w2T, const float* __restrict__ ge_w2,
    const float* __restrict__ b2,
    float* __restrict__ w2q, float* __restrict__ pos, float* __restrict__ scl,
    float* __restrict__ stage) {
  const int bk = blockIdx.x, t = threadIdx.x;
  __shared__ float u[256], h[256], lnv[256], phl[512], red[8];
  phl[t] = ph[bk * 512 + t];
  phl[256 + t] = ph[bk * 512 + 256 + t];
  h[t] = sf[bk * 260 + t];
  __syncthreads();
  // upd = ph @ ge_w2 + b2  (coalesced column reads of ge_w2)
  float uu = b2[t];
#pragma unroll 8
  for (int j = 0; j < ND2; j++) uu = fmaf(phl[j], ge_w2[(size_t)j * ND + t], uu);
  u[t] = uu;
  __syncthreads();
  const float* wi = gT;             // [256][768]
  const float* wh = gT + 196608;    // [256][768]
  float a0 = 0.f, a1 = 0.f, a2 = 0.f, c0 = 0.f, c1 = 0.f, c2 = 0.f;
#pragma unroll 4
  for (int d = 0; d < ND; d++) {
    const float ud = u[d], hd = h[d];
    const float* wid = wi + (size_t)d * 768;
    const float* whd = wh + (size_t)d * 768;
    a0 = fmaf(ud, wid[t], a0);
    a1 = fmaf(ud, wid[256 + t], a1);
    a2 = fmaf(ud, wid[512 + t], a2);
    c0 = fmaf(hd, whd[t], c0);
    c1 = fmaf(hd, whd[256 + t], c1);
    c2 = fmaf(hd, whd[512 + t], c2);
  }
  const float r = 1.0f / (1.0f + expf(-(a0 + bih[t] + c0 + bhh[t])));
  const float z = 1.0f / (1.0f + expf(-(a1 + bih[256 + t] + c1 + bhh[256 + t])));
  const float nw = tanhf(a2 + bih[512 + t] + r * (c2 + bhh[512 + t]));
  const float ns = (1.0f - z) * nw + z * h[t];
  sf[bk * 260 + t] = ns;
  // LN of new slots
  float s2 = ns, ss = ns * ns;
#pragma unroll
  for (int m = 32; m >= 1; m >>= 1) { s2 += __shfl_xor(s2, m); ss += __shfl_xor(ss, m); }
  const int wv = t >> 6;
  if ((t & 63) == 0) { red[wv] = s2; red[4 + wv] = ss; }
  __syncthreads();
  const float S = red[0] + red[1] + red[2] + red[3];
  const float SS = red[4] + red[5] + red[6] + red[7];
  const float mean = S * (1.0f / ND);
  const float var = SS * (1.0f / ND) - mean * mean;
  const float rstd = rsqrtf(var + LNEPS);
  lnv[t] = (ns - mean) * rstd * nsg[t] + nsb[t];
  // moments -> pos/scl (read stage BEFORE zeroing)
  if (t == 0) {
    const float Sa = stage[bk * 8 + 0];
    const float G0 = stage[bk * 8 + 1];
    const float G1 = stage[bk * 8 + 2];
    const float Q0 = stage[bk * 8 + 3];
    const float Q1 = stage[bk * 8 + 4];
    const float W = Sa + (float)NN * EPSA;
    const float sc0 = sqrtf(fmaxf(Q0 - 2.0f * G0 * G0 + G0 * G0 * W, 0.f));
    const float sc1 = sqrtf(fmaxf(Q1 - 2.0f * G1 * G1 + G1 * G1 * W, 0.f));
    const float sc0c = fminf(fmaxf(sc0, 1e-3f), 2.0f);
    const float sc1c = fminf(fmaxf(sc1, 1e-3f), 2.0f);
    sf[bk * 260 + 256] = G0;
    sf[bk * 260 + 257] = G1;
    sf[bk * 260 + 258] = sc0c;
    sf[bk * 260 + 259] = sc1c;
    pos[bk * 2 + 0] = fminf(fmaxf(G0, -1.0f), 1.0f);
    pos[bk * 2 + 1] = fminf(fmaxf(G1, -1.0f), 1.0f);
    scl[bk * 2 + 0] = sc0c;
    scl[bk * 2 + 1] = sc1c;
  }
  __syncthreads();  // lnv ready; stage reads done
  if (t < 8) stage[bk * 8 + t] = 0.f;
  // q projection
  float qt = 0.f;
#pragma unroll 8
  for (int e = 0; e < ND; e++) qt = fmaf(lnv[e], wq[e * ND + t], qt);
  // qb2
  float qb = b2[t] * qt;
#pragma unroll
  for (int m = 32; m >= 1; m >>= 1) qb += __shfl_xor(qb, m);
  __syncthreads();  // u[] free for reuse as q-stage; red free
  u[t] = qt;
  if ((t & 63) == 0) red[wv] = qb;
  __syncthreads();
  // w2q
  float w0 = 0.f, w1v = 0.f;
#pragma unroll 4
  for (int d = 0; d < ND; d++) {
    const float qd = u[d];
    w0 = fmaf(qd, bf2f(w2T[d * 512 + t]), w0);
    w1v = fmaf(qd, bf2f(w2T[d * 512 + 256 + t]), w1v);
  }
  w2q[bk * 512 + t] = w0;
  w2q[bk * 512 + 256 + t] = w1v;
  if (t == 0) stage[bk * 8 + 5] = red[0] + red[1] + red[2] + red[3];
  // zero ph for next step
  ph[bk * 512 + t] = 0.f;
  ph[bk * 512 + 256 + t] = 0.f;
}

// ---------------- finalize ----------------
__global__ __launch_bounds__(256) void k_finalize(
    const float* __restrict__ sf, const float* __restrict__ attn0,
    const float* __restrict__ pos, const float* __restrict__ scl,
    const float* __restrict__ stage, float* __restrict__ out) {
  const int bk = blockIdx.x, t = threadIdx.x;
  out[bk * 260 + t] = sf[bk * 260 + t];
  if (t == 0) {
    const float Sa = stage[bk * 8 + 0];
    const float G0 = stage[bk * 8 + 1];
    const float G1 = stage[bk * 8 + 2];
    const float Q0 = stage[bk * 8 + 3];
    const float Q1 = stage[bk * 8 + 4];
    const float W = Sa + (float)NN * EPSA;
    const float sc0 = sqrtf(fmaxf(Q0 - 2.0f * G0 * G0 + G0 * G0 * W, 0.f));
    const float sc1 = sqrtf(fmaxf(Q1 - 2.0f * G1 * G1 + G1 * G1 * W, 0.f));
    out[bk * 260 + 256] = G0;
    out[bk * 260 + 257] = G1;
    out[bk * 260 + 258] = fminf(fmaxf(sc0, 1e-3f), 2.0f);
    out[bk * 260 + 259] = fminf(fmaxf(sc1, 1e-3f), 2.0f);
  }
  const float p0 = pos[bk * 2 + 0], p1 = pos[bk * 2 + 1];
  const float s0 = scl[bk * 2 + 0] * 5.0f, s1 = scl[bk * 2 + 1] * 5.0f;
#pragma unroll
  for (int i = 0; i < 4; i++) {
    const int n = t + 256 * i;
    out[16640 + bk * NN + n] = attn0[(size_t)bk * NN + n];
    const float gx = -1.0f + GSTEP * (float)(n >> 5);
    const float gy = -1.0f + GSTEP * (float)(n & 31);
    float2 v;
    v.x = (gx - p0) / s0;
    v.y = (gy - p1) / s1;
    *(float2*)(out + 16640 + 65536 + ((size_t)bk * NN + n) * 2) = v;
  }
}

extern "C" void kernel_launch(void* const* d_in, const int* in_sizes, int n_in,
                              void* d_out, int out_size, void* d_ws, size_t ws_size,
                              hipStream_t stream) {
  const float* inputs   = (const float*)d_in[0];
  const float* cond     = (const float*)d_in[1];
  const float* ni_g     = (const float*)d_in[2];
  const float* ni_b     = (const float*)d_in[3];
  const float* ns_g     = (const float*)d_in[4];
  const float* ns_b     = (const float*)d_in[5];
  const float* wq       = (const float*)d_in[6];
  const float* wk       = (const float*)d_in[7];
  const float* wv       = (const float*)d_in[8];
  const float* gp_w     = (const float*)d_in[9];
  const float* gp_b     = (const float*)d_in[10];
  const float* ge_ln_g  = (const float*)d_in[11];
  const float* ge_ln_b  = (const float*)d_in[12];
  const float* ge_w1    = (const float*)d_in[13];
  const float* ge_b1    = (const float*)d_in[14];
  const float* ge_w2    = (const float*)d_in[15];
  const float* ge_b2    = (const float*)d_in[16];
  const float* gru_wih  = (const float*)d_in[17];
  const float* gru_whh  = (const float*)d_in[18];
  const float* gru_bih  = (const float*)d_in[19];
  const float* gru_bhh  = (const float*)d_in[20];

  float* ws   = (float*)d_ws;
  float* kbuf = ws;                  // 8*1024*256
  float* vbuf = kbuf + 2097152;      // 8*1024*256
  float* sf   = vbuf + 2097152;      // 64*260
  float* w2qb = sf + 16640;          // 64*512
  float* posb = w2qb + 32768;        // 64*2 (padded)
  float* sclb = posb + 128;          // 64*2 (padded)
  float* dotsb = sclb + 128;         // 64*1024
  float* at0  = dotsb + 65536;       // 64*1024
  float* phb  = at0 + 65536;         // 64*512
  float* stag = phb + 32768;         // 64*8
  float* gruT = stag + 512;          // 2*256*768
  short* w1T  = (short*)(gruT + 393216);  // 512*256 bf16
  short* w2T  = w1T + 131072;             // 256*512 bf16
  short* wkT  = w2T + 131072;             // 256*256 bf16
  short* wvT  = wkT + 65536;              // 256*256 bf16

  float* out = (float*)d_out;

  hipMemcpyAsync(sf, cond, 16640 * sizeof(float), hipMemcpyDeviceToDevice, stream);

  k_cvt_all<<<3072, 256, 0, stream>>>(ge_w1, ge_w2, wk, wv, gru_wih, gru_whh,
                                      w1T, w2T, wkT, wvT, gruT);
  k_gemm_kv_mfma<<<dim3(128, 1, 2), 256, 0, stream>>>(inputs, ni_g, ni_b,
                                                      wkT, wvT, kbuf, vbuf);
  k_prep<<<NBK, 256, 0, stream>>>(sf, ns_g, ns_b, wq, w2T, ge_b2,
                                  w2qb, posb, sclb, phb, stag);

  for (int s = 0; s < 4; s++) {
    k_fused_mfma<<<dim3(16, NBK), 256, 0, stream>>>(
        kbuf, posb, sclb, gp_w, gp_b, ge_ln_g, ge_ln_b, w1T, ge_b1,
        w2qb, dotsb, at0, stag, phb, 0);
    k_softmax_reduce<<<32, 256, 0, stream>>>(dotsb, at0, stag);
    if (s < 3) {
      k_fused_mfma<<<dim3(16, NBK), 256, 0, stream>>>(
          vbuf, posb, sclb, gp_w, gp_b, ge_ln_g, ge_ln_b, w1T, ge_b1,
          w2qb, dotsb, at0, stag, phb, 1);
      k_gruprep<<<NBK, 256, 0, stream>>>(phb, sf, gruT, gru_bih, gru_bhh,
                                         ns_g, ns_b, wq, w2T, ge_w2, ge_b2,
                                         w2qb, posb, sclb, stag);
    }
  }

  k_finalize<<<NBK, 256, 0, stream>>>(sf, at0, posb, sclb, stag, out);
}